// Round 1
// baseline (1791.675 us; speedup 1.0000x reference)
//
#include <hip/hip_runtime.h>
#include <math.h>

#define NN 50000
#define EE 800000
#define EF (EE + NN)
#define DD 64
#define NEG_SLOPE 0.2f

__device__ __forceinline__ int src_of(const int* __restrict__ src, int e) {
  return (e < EE) ? src[e] : (e - EE);
}
__device__ __forceinline__ int dst_of(const int* __restrict__ dst, int e) {
  return (e < EE) ? dst[e] : (e - EE);
}

// ---------------- CSR build ----------------

__global__ void k_zero(int* __restrict__ p, int n) {
  int i = blockIdx.x * blockDim.x + threadIdx.x;
  if (i < n) p[i] = 0;
}

__global__ void k_degree(const int* __restrict__ dst, int* __restrict__ deg) {
  int e = blockIdx.x * blockDim.x + threadIdx.x;
  if (e < EF) atomicAdd(&deg[dst_of(dst, e)], 1);
}

// single block, 1024 threads: exclusive scan of deg[0..NN) -> rowstart[0..NN]
__global__ void k_scan(const int* __restrict__ deg, int* __restrict__ rowstart) {
  __shared__ int wsum[16];
  __shared__ int chunk_total;
  __shared__ int carry_s;
  int tid = threadIdx.x;
  int lane = tid & 63;
  int wid = tid >> 6;
  if (tid == 0) carry_s = 0;
  __syncthreads();
  for (int base = 0; base < NN; base += 1024) {
    int i = base + tid;
    int v = (i < NN) ? deg[i] : 0;
    int s = v;
#pragma unroll
    for (int off = 1; off < 64; off <<= 1) {
      int t = __shfl_up(s, off, 64);
      if (lane >= off) s += t;
    }
    if (lane == 63) wsum[wid] = s;
    __syncthreads();
    if (wid == 0) {
      int wv = (lane < 16) ? wsum[lane] : 0;
      int ws2 = wv;
#pragma unroll
      for (int off = 1; off < 16; off <<= 1) {
        int t = __shfl_up(ws2, off, 64);
        if (lane >= off) ws2 += t;
      }
      if (lane < 16) wsum[lane] = ws2 - wv;  // exclusive wave prefix
      if (lane == 15) chunk_total = ws2;     // inclusive total of chunk
    }
    __syncthreads();
    int excl = carry_s + wsum[wid] + (s - v);
    if (i < NN) rowstart[i] = excl;
    __syncthreads();
    if (tid == 0) carry_s += chunk_total;
    __syncthreads();
  }
  if (tid == 0) rowstart[NN] = carry_s;
}

__global__ void k_bucket(const int* __restrict__ dst, const int* __restrict__ rowstart,
                         int* __restrict__ cursor, int* __restrict__ eidx) {
  int e = blockIdx.x * blockDim.x + threadIdx.x;
  if (e < EF) {
    int d = dst_of(dst, e);
    int pos = atomicAdd(&cursor[d], 1);
    eidx[rowstart[d] + pos] = e;
  }
}

// ---------------- GAT ----------------

// el = x @ Wsrc^T + bsrc ; er = x @ Wdst^T + bdst
__global__ __launch_bounds__(256) void k_linear2(
    const float* __restrict__ x,
    const float* __restrict__ Wsrc, const float* __restrict__ bsrc,
    const float* __restrict__ Wdst, const float* __restrict__ bdst,
    float* __restrict__ el, float* __restrict__ er) {
  __shared__ float ws[DD * 65];
  __shared__ float wd[DD * 65];
  int tid = threadIdx.x;
  for (int i = tid; i < DD * DD; i += 256) {
    int r = i >> 6, c = i & 63;
    ws[r * 65 + c] = Wsrc[i];
    wd[r * 65 + c] = Wdst[i];
  }
  __syncthreads();
  int lane = tid & 63;
  int wid = tid >> 6;
  const int NPT = 8;
  int n0 = (blockIdx.x * 4 + wid) * NPT;
  float acc_s[NPT], acc_d[NPT];
#pragma unroll
  for (int g = 0; g < NPT; g++) { acc_s[g] = 0.f; acc_d[g] = 0.f; }
#pragma unroll 4
  for (int d = 0; d < DD; d++) {
    float a = ws[lane * 65 + d];
    float b = wd[lane * 65 + d];
#pragma unroll
    for (int g = 0; g < NPT; g++) {
      int n = n0 + g; n = (n < NN) ? n : (NN - 1);
      float xv = x[n * DD + d];
      acc_s[g] = fmaf(xv, a, acc_s[g]);
      acc_d[g] = fmaf(xv, b, acc_d[g]);
    }
  }
  float bs = bsrc[lane], bd = bdst[lane];
#pragma unroll
  for (int g = 0; g < NPT; g++) {
    int n = n0 + g;
    if (n < NN) {
      el[n * DD + lane] = acc_s[g] + bs;
      er[n * DD + lane] = acc_d[g] + bd;
    }
  }
}

// one wave per edge: score[e] = dot(leaky_relu(el[s]+er[t]), attn)
__global__ __launch_bounds__(256) void k_edge_score(
    const float* __restrict__ el, const float* __restrict__ er,
    const float* __restrict__ attn,
    const int* __restrict__ src, const int* __restrict__ dst,
    float* __restrict__ score) {
  int lane = threadIdx.x & 63;
  int e = blockIdx.x * 4 + (threadIdx.x >> 6);
  if (e >= EF) return;
  int s = src_of(src, e);
  int t = dst_of(dst, e);
  float v = el[s * DD + lane] + er[t * DD + lane];
  v = (v > 0.f) ? v : NEG_SLOPE * v;
  v *= attn[lane];
#pragma unroll
  for (int off = 32; off > 0; off >>= 1) v += __shfl_xor(v, off, 64);
  if (lane == 0) score[e] = v;
}

// one wave per node: softmax over incoming edges, weighted sum of el[src], elu
__global__ __launch_bounds__(256) void k_gat_agg(
    const float* __restrict__ el, const float* __restrict__ score,
    const int* __restrict__ rowstart, const int* __restrict__ eidx,
    const int* __restrict__ src,
    float* __restrict__ out) {
  int lane = threadIdx.x & 63;
  int n = blockIdx.x * 4 + (threadIdx.x >> 6);
  if (n >= NN) return;
  int r0 = rowstart[n], r1 = rowstart[n + 1];
  float m = -INFINITY;
  for (int i = r0 + lane; i < r1; i += 64) m = fmaxf(m, score[eidx[i]]);
#pragma unroll
  for (int off = 32; off > 0; off >>= 1) m = fmaxf(m, __shfl_xor(m, off, 64));
  float den = 0.f, acc = 0.f;
  for (int i = r0; i < r1; i++) {
    int e = eidx[i];
    float ex = expf(score[e] - m);
    int s = src_of(src, e);
    den += ex;
    acc = fmaf(ex, el[s * DD + lane], acc);
  }
  float o = acc / den;
  out[n * DD + lane] = (o > 0.f) ? o : expm1f(o);
}

// ---------------- GGC ----------------

// trans[t] = h @ W[t]^T + b[t], t=0,1
__global__ __launch_bounds__(256) void k_trans(
    const float* __restrict__ h,
    const float* __restrict__ W,   // (2,64,64)
    const float* __restrict__ b,   // (2,64)
    float* __restrict__ trans) {   // (2,NN,64)
  __shared__ float w0[DD * 65];
  __shared__ float w1[DD * 65];
  int tid = threadIdx.x;
  for (int i = tid; i < DD * DD; i += 256) {
    int r = i >> 6, c = i & 63;
    w0[r * 65 + c] = W[i];
    w1[r * 65 + c] = W[DD * DD + i];
  }
  __syncthreads();
  int lane = tid & 63;
  int wid = tid >> 6;
  const int NPT = 8;
  int n0 = (blockIdx.x * 4 + wid) * NPT;
  float a0[NPT], a1[NPT];
#pragma unroll
  for (int g = 0; g < NPT; g++) { a0[g] = 0.f; a1[g] = 0.f; }
#pragma unroll 4
  for (int d = 0; d < DD; d++) {
    float c0 = w0[lane * 65 + d];
    float c1 = w1[lane * 65 + d];
#pragma unroll
    for (int g = 0; g < NPT; g++) {
      int n = n0 + g; n = (n < NN) ? n : (NN - 1);
      float hv = h[n * DD + d];
      a0[g] = fmaf(hv, c0, a0[g]);
      a1[g] = fmaf(hv, c1, a1[g]);
    }
  }
  float b0 = b[lane], b1 = b[DD + lane];
#pragma unroll
  for (int g = 0; g < NPT; g++) {
    int n = n0 + g;
    if (n < NN) {
      trans[n * DD + lane] = a0[g] + b0;
      trans[(NN + n) * DD + lane] = a1[g] + b1;
    }
  }
}

// one wave per node: agg[n] = sum over in-edges of trans[etype, src]
__global__ __launch_bounds__(256) void k_ggc_agg(
    const float* __restrict__ trans,
    const int* __restrict__ rowstart, const int* __restrict__ eidx,
    const int* __restrict__ src, const int* __restrict__ etypes,
    float* __restrict__ agg) {
  int lane = threadIdx.x & 63;
  int n = blockIdx.x * 4 + (threadIdx.x >> 6);
  if (n >= NN) return;
  int r0 = rowstart[n], r1 = rowstart[n + 1];
  float acc = 0.f;
  for (int i = r0; i < r1; i++) {
    int e = eidx[i];
    int t = etypes[e];
    int s = src_of(src, e);
    acc += trans[(t * NN + s) * DD + lane];
  }
  agg[n * DD + lane] = acc;
}

// fused GRU cell: gi = agg@Wih^T+bih, gh = h@Whh^T+bhh (two LDS phases), update
__global__ __launch_bounds__(256) void k_gru(
    const float* __restrict__ agg, const float* __restrict__ h_in,
    const float* __restrict__ Wih, const float* __restrict__ bih,
    const float* __restrict__ Whh, const float* __restrict__ bhh,
    float* __restrict__ h_out) {
  __shared__ float w[192 * 65];
  int tid = threadIdx.x;
  int lane = tid & 63;
  int wid = tid >> 6;
  const int NPT = 4;
  int n0 = (blockIdx.x * 4 + wid) * NPT;  // grid 3125 * 16 = 50000 exact

  for (int i = tid; i < 192 * 64; i += 256) {
    int r = i >> 6, c = i & 63;
    w[r * 65 + c] = Wih[i];
  }
  __syncthreads();

  float ir[NPT], iz[NPT], ic[NPT];
#pragma unroll
  for (int g = 0; g < NPT; g++) { ir[g] = 0.f; iz[g] = 0.f; ic[g] = 0.f; }
#pragma unroll 4
  for (int d = 0; d < DD; d++) {
    float wr = w[lane * 65 + d];
    float wz = w[(64 + lane) * 65 + d];
    float wc = w[(128 + lane) * 65 + d];
#pragma unroll
    for (int g = 0; g < NPT; g++) {
      float a = agg[(n0 + g) * DD + d];
      ir[g] = fmaf(a, wr, ir[g]);
      iz[g] = fmaf(a, wz, iz[g]);
      ic[g] = fmaf(a, wc, ic[g]);
    }
  }
  __syncthreads();
  for (int i = tid; i < 192 * 64; i += 256) {
    int r = i >> 6, c = i & 63;
    w[r * 65 + c] = Whh[i];
  }
  __syncthreads();

  float hr[NPT], hz[NPT], hc[NPT];
#pragma unroll
  for (int g = 0; g < NPT; g++) { hr[g] = 0.f; hz[g] = 0.f; hc[g] = 0.f; }
#pragma unroll 4
  for (int d = 0; d < DD; d++) {
    float wr = w[lane * 65 + d];
    float wz = w[(64 + lane) * 65 + d];
    float wc = w[(128 + lane) * 65 + d];
#pragma unroll
    for (int g = 0; g < NPT; g++) {
      float h = h_in[(n0 + g) * DD + d];
      hr[g] = fmaf(h, wr, hr[g]);
      hz[g] = fmaf(h, wz, hz[g]);
      hc[g] = fmaf(h, wc, hc[g]);
    }
  }

  float b_ir = bih[lane], b_iz = bih[64 + lane], b_ic = bih[128 + lane];
  float b_hr = bhh[lane], b_hz = bhh[64 + lane], b_hc = bhh[128 + lane];
#pragma unroll
  for (int g = 0; g < NPT; g++) {
    int n = n0 + g;
    float r = 1.f / (1.f + expf(-((ir[g] + b_ir) + (hr[g] + b_hr))));
    float z = 1.f / (1.f + expf(-((iz[g] + b_iz) + (hz[g] + b_hz))));
    float c = tanhf((ic[g] + b_ic) + r * (hc[g] + b_hc));
    float hprev = h_in[n * DD + lane];
    h_out[n * DD + lane] = (1.f - z) * c + z * hprev;
  }
}

// ---------------- launch ----------------

extern "C" void kernel_launch(void* const* d_in, const int* in_sizes, int n_in,
                              void* d_out, int out_size, void* d_ws, size_t ws_size,
                              hipStream_t stream) {
  const float* x = (const float*)d_in[0];
  const int* src = (const int*)d_in[1];
  const int* dst = (const int*)d_in[2];
  const int* etypes = (const int*)d_in[3];

  float* out = (float*)d_out;

  float* el = (float*)d_ws;            // NN*DD
  float* er = el + NN * DD;            // NN*DD
  float* score = er + NN * DD;         // EF
  float* trans = score + EF;           // 2*NN*DD
  float* agg = trans + 2 * NN * DD;    // NN*DD
  float* htmp = agg + NN * DD;         // NN*DD
  int* deg = (int*)(htmp + NN * DD);   // NN
  int* cursor = deg + NN;              // NN
  int* rowstart = cursor + NN;         // NN+1
  int* eidx = rowstart + (NN + 1);     // EF

  // CSR (grouped by dst) rebuilt every call (ws is re-poisoned)
  k_zero<<<(2 * NN + 255) / 256, 256, 0, stream>>>(deg, 2 * NN);
  k_degree<<<(EF + 255) / 256, 256, 0, stream>>>(dst, deg);
  k_scan<<<1, 1024, 0, stream>>>(deg, rowstart);
  k_bucket<<<(EF + 255) / 256, 256, 0, stream>>>(dst, rowstart, cursor, eidx);

  for (int l = 0; l < 2; l++) {
    int base = 4 + 11 * l;
    const float* Wsrc = (const float*)d_in[base + 0];
    const float* bsrc = (const float*)d_in[base + 1];
    const float* Wdst = (const float*)d_in[base + 2];
    const float* bdst = (const float*)d_in[base + 3];
    const float* attn = (const float*)d_in[base + 4];
    const float* gW   = (const float*)d_in[base + 5];
    const float* gb   = (const float*)d_in[base + 6];
    const float* Wih  = (const float*)d_in[base + 7];
    const float* bih  = (const float*)d_in[base + 8];
    const float* Whh  = (const float*)d_in[base + 9];
    const float* bhh  = (const float*)d_in[base + 10];

    const float* xin = (l == 0) ? x : (out + 1 * (size_t)NN * DD);
    float* emb_gat = out + (size_t)(2 * l) * NN * DD;
    float* emb_ggc = out + (size_t)(2 * l + 1) * NN * DD;

    // GATv2
    k_linear2<<<1563, 256, 0, stream>>>(xin, Wsrc, bsrc, Wdst, bdst, el, er);
    k_edge_score<<<(EF + 3) / 4, 256, 0, stream>>>(el, er, attn, src, dst, score);
    k_gat_agg<<<(NN + 3) / 4, 256, 0, stream>>>(el, score, rowstart, eidx, src, emb_gat);

    // GGC step 1
    k_trans<<<1563, 256, 0, stream>>>(emb_gat, gW, gb, trans);
    k_ggc_agg<<<(NN + 3) / 4, 256, 0, stream>>>(trans, rowstart, eidx, src, etypes, agg);
    k_gru<<<3125, 256, 0, stream>>>(agg, emb_gat, Wih, bih, Whh, bhh, htmp);

    // GGC step 2
    k_trans<<<1563, 256, 0, stream>>>(htmp, gW, gb, trans);
    k_ggc_agg<<<(NN + 3) / 4, 256, 0, stream>>>(trans, rowstart, eidx, src, etypes, agg);
    k_gru<<<3125, 256, 0, stream>>>(agg, htmp, Wih, bih, Whh, bhh, emb_ggc);
  }
}

// Round 2
// 1058.122 us; speedup vs baseline: 1.6933x; 1.6933x over previous
//
#include <hip/hip_runtime.h>
#include <math.h>

#define NN 50000
#define EE 800000
#define EF (EE + NN)
#define DD 64
#define NEG_SLOPE 0.2f

__device__ __forceinline__ int src_of(const int* __restrict__ src, int e) {
  return (e < EE) ? src[e] : (e - EE);
}
__device__ __forceinline__ int dst_of(const int* __restrict__ dst, int e) {
  return (e < EE) ? dst[e] : (e - EE);
}

// ---------------- CSR build ----------------

__global__ void k_zero(int* __restrict__ p, int n) {
  int i = blockIdx.x * blockDim.x + threadIdx.x;
  if (i < n) p[i] = 0;
}

__global__ void k_degree(const int* __restrict__ dst, int* __restrict__ deg) {
  int e = blockIdx.x * blockDim.x + threadIdx.x;
  if (e < EF) atomicAdd(&deg[dst_of(dst, e)], 1);
}

// single block, 1024 threads: exclusive scan of deg[0..NN) -> rowstart[0..NN]
__global__ void k_scan(const int* __restrict__ deg, int* __restrict__ rowstart) {
  __shared__ int wsum[16];
  __shared__ int chunk_total;
  __shared__ int carry_s;
  int tid = threadIdx.x;
  int lane = tid & 63;
  int wid = tid >> 6;
  if (tid == 0) carry_s = 0;
  __syncthreads();
  for (int base = 0; base < NN; base += 1024) {
    int i = base + tid;
    int v = (i < NN) ? deg[i] : 0;
    int s = v;
#pragma unroll
    for (int off = 1; off < 64; off <<= 1) {
      int t = __shfl_up(s, off, 64);
      if (lane >= off) s += t;
    }
    if (lane == 63) wsum[wid] = s;
    __syncthreads();
    if (wid == 0) {
      int wv = (lane < 16) ? wsum[lane] : 0;
      int ws2 = wv;
#pragma unroll
      for (int off = 1; off < 16; off <<= 1) {
        int t = __shfl_up(ws2, off, 64);
        if (lane >= off) ws2 += t;
      }
      if (lane < 16) wsum[lane] = ws2 - wv;  // exclusive wave prefix
      if (lane == 15) chunk_total = ws2;     // inclusive total of chunk
    }
    __syncthreads();
    int excl = carry_s + wsum[wid] + (s - v);
    if (i < NN) rowstart[i] = excl;
    __syncthreads();
    if (tid == 0) carry_s += chunk_total;
    __syncthreads();
  }
  if (tid == 0) rowstart[NN] = carry_s;
}

// bucket edges by dst, writing CSR-order companion arrays (no eidx indirection)
__global__ void k_bucket(const int* __restrict__ src, const int* __restrict__ dst,
                         const int* __restrict__ etypes,
                         const int* __restrict__ rowstart, int* __restrict__ cursor,
                         int* __restrict__ csr_src, int* __restrict__ csr_dst,
                         int* __restrict__ csr_et) {
  int e = blockIdx.x * blockDim.x + threadIdx.x;
  if (e < EF) {
    int d = dst_of(dst, e);
    int pos = atomicAdd(&cursor[d], 1);
    int i = rowstart[d] + pos;
    csr_src[i] = src_of(src, e);
    csr_dst[i] = d;
    csr_et[i] = etypes[e];
  }
}

// ---------------- GAT ----------------

// el = x @ Wsrc^T + bsrc ; er = x @ Wdst^T + bdst
__global__ __launch_bounds__(256) void k_linear2(
    const float* __restrict__ x,
    const float* __restrict__ Wsrc, const float* __restrict__ bsrc,
    const float* __restrict__ Wdst, const float* __restrict__ bdst,
    float* __restrict__ el, float* __restrict__ er) {
  __shared__ float ws[DD * 65];
  __shared__ float wd[DD * 65];
  int tid = threadIdx.x;
  for (int i = tid; i < DD * DD; i += 256) {
    int r = i >> 6, c = i & 63;
    ws[r * 65 + c] = Wsrc[i];
    wd[r * 65 + c] = Wdst[i];
  }
  __syncthreads();
  int lane = tid & 63;
  int wid = tid >> 6;
  const int NPT = 8;
  int n0 = (blockIdx.x * 4 + wid) * NPT;
  float acc_s[NPT], acc_d[NPT];
#pragma unroll
  for (int g = 0; g < NPT; g++) { acc_s[g] = 0.f; acc_d[g] = 0.f; }
#pragma unroll 4
  for (int d = 0; d < DD; d++) {
    float a = ws[lane * 65 + d];
    float b = wd[lane * 65 + d];
#pragma unroll
    for (int g = 0; g < NPT; g++) {
      int n = n0 + g; n = (n < NN) ? n : (NN - 1);
      float xv = x[n * DD + d];
      acc_s[g] = fmaf(xv, a, acc_s[g]);
      acc_d[g] = fmaf(xv, b, acc_d[g]);
    }
  }
  float bs = bsrc[lane], bd = bdst[lane];
#pragma unroll
  for (int g = 0; g < NPT; g++) {
    int n = n0 + g;
    if (n < NN) {
      el[n * DD + lane] = acc_s[g] + bs;
      er[n * DD + lane] = acc_d[g] + bd;
    }
  }
}

// thread per CSR position: score_csr[i] = dot(leaky_relu(el[s]+er[t]), attn)
// serial-d in registers, float4 rows, no cross-lane ops
__global__ __launch_bounds__(256) void k_edge_score(
    const float* __restrict__ el, const float* __restrict__ er,
    const float* __restrict__ attn,
    const int* __restrict__ csr_src, const int* __restrict__ csr_dst,
    float* __restrict__ score_csr) {
  __shared__ float sattn[DD];
  int tid = threadIdx.x;
  if (tid < DD) sattn[tid] = attn[tid];
  __syncthreads();
  int i = blockIdx.x * 256 + tid;
  if (i >= EF) return;
  int s = csr_src[i];
  int t = csr_dst[i];
  const float4* a4 = (const float4*)(el + (size_t)s * DD);
  const float4* b4 = (const float4*)(er + (size_t)t * DD);
  float acc = 0.f;
#pragma unroll 4
  for (int q = 0; q < 16; q++) {
    float4 ea = a4[q];
    float4 eb = b4[q];
    float v;
    v = ea.x + eb.x; v = (v > 0.f) ? v : NEG_SLOPE * v; acc = fmaf(v, sattn[4 * q + 0], acc);
    v = ea.y + eb.y; v = (v > 0.f) ? v : NEG_SLOPE * v; acc = fmaf(v, sattn[4 * q + 1], acc);
    v = ea.z + eb.z; v = (v > 0.f) ? v : NEG_SLOPE * v; acc = fmaf(v, sattn[4 * q + 2], acc);
    v = ea.w + eb.w; v = (v > 0.f) ? v : NEG_SLOPE * v; acc = fmaf(v, sattn[4 * q + 3], acc);
  }
  score_csr[i] = acc;
}

// wave per node: softmax over contiguous score_csr slice, then 4-way-unrolled
// weighted gather of el rows, elu
__global__ __launch_bounds__(256) void k_gat_agg(
    const float* __restrict__ el, float* __restrict__ score_csr,
    const int* __restrict__ rowstart, const int* __restrict__ csr_src,
    float* __restrict__ out) {
  int lane = threadIdx.x & 63;
  int n = blockIdx.x * 4 + (threadIdx.x >> 6);
  if (n >= NN) return;
  int r0 = rowstart[n], r1 = rowstart[n + 1];
  // phase A1: max (coalesced strided read)
  float m = -INFINITY;
  for (int i = r0 + lane; i < r1; i += 64) m = fmaxf(m, score_csr[i]);
#pragma unroll
  for (int off = 32; off > 0; off >>= 1) m = fmaxf(m, __shfl_xor(m, off, 64));
  // phase A2: exp + den, write ex back in place (slice is exclusive to node n)
  float den = 0.f;
  for (int i = r0 + lane; i < r1; i += 64) {
    float ex = __expf(score_csr[i] - m);
    den += ex;
    score_csr[i] = ex;
  }
#pragma unroll
  for (int off = 32; off > 0; off >>= 1) den += __shfl_xor(den, off, 64);
  // phase B: weighted row gather, 4 accumulators for MLP
  float a0 = 0.f, a1 = 0.f, a2 = 0.f, a3 = 0.f;
  int i = r0;
  for (; i + 4 <= r1; i += 4) {
    int s0 = csr_src[i + 0], s1 = csr_src[i + 1];
    int s2 = csr_src[i + 2], s3 = csr_src[i + 3];
    float w0 = score_csr[i + 0], w1 = score_csr[i + 1];
    float w2 = score_csr[i + 2], w3 = score_csr[i + 3];
    a0 = fmaf(w0, el[(size_t)s0 * DD + lane], a0);
    a1 = fmaf(w1, el[(size_t)s1 * DD + lane], a1);
    a2 = fmaf(w2, el[(size_t)s2 * DD + lane], a2);
    a3 = fmaf(w3, el[(size_t)s3 * DD + lane], a3);
  }
  for (; i < r1; i++) {
    a0 = fmaf(score_csr[i], el[(size_t)csr_src[i] * DD + lane], a0);
  }
  float o = ((a0 + a1) + (a2 + a3)) / den;
  out[(size_t)n * DD + lane] = (o > 0.f) ? o : expm1f(o);
}

// ---------------- GGC ----------------

// trans[t] = h @ W[t]^T + b[t], t=0,1
__global__ __launch_bounds__(256) void k_trans(
    const float* __restrict__ h,
    const float* __restrict__ W,   // (2,64,64)
    const float* __restrict__ b,   // (2,64)
    float* __restrict__ trans) {   // (2,NN,64)
  __shared__ float w0[DD * 65];
  __shared__ float w1[DD * 65];
  int tid = threadIdx.x;
  for (int i = tid; i < DD * DD; i += 256) {
    int r = i >> 6, c = i & 63;
    w0[r * 65 + c] = W[i];
    w1[r * 65 + c] = W[DD * DD + i];
  }
  __syncthreads();
  int lane = tid & 63;
  int wid = tid >> 6;
  const int NPT = 8;
  int n0 = (blockIdx.x * 4 + wid) * NPT;
  float a0[NPT], a1[NPT];
#pragma unroll
  for (int g = 0; g < NPT; g++) { a0[g] = 0.f; a1[g] = 0.f; }
#pragma unroll 4
  for (int d = 0; d < DD; d++) {
    float c0 = w0[lane * 65 + d];
    float c1 = w1[lane * 65 + d];
#pragma unroll
    for (int g = 0; g < NPT; g++) {
      int n = n0 + g; n = (n < NN) ? n : (NN - 1);
      float hv = h[n * DD + d];
      a0[g] = fmaf(hv, c0, a0[g]);
      a1[g] = fmaf(hv, c1, a1[g]);
    }
  }
  float b0 = b[lane], b1 = b[DD + lane];
#pragma unroll
  for (int g = 0; g < NPT; g++) {
    int n = n0 + g;
    if (n < NN) {
      trans[(size_t)n * DD + lane] = a0[g] + b0;
      trans[(size_t)(NN + n) * DD + lane] = a1[g] + b1;
    }
  }
}

// wave per node: agg[n] = sum over in-edges of trans[etype, src], 4-way unroll
__global__ __launch_bounds__(256) void k_ggc_agg(
    const float* __restrict__ trans,
    const int* __restrict__ rowstart, const int* __restrict__ csr_src,
    const int* __restrict__ csr_et,
    float* __restrict__ agg) {
  int lane = threadIdx.x & 63;
  int n = blockIdx.x * 4 + (threadIdx.x >> 6);
  if (n >= NN) return;
  int r0 = rowstart[n], r1 = rowstart[n + 1];
  float a0 = 0.f, a1 = 0.f, a2 = 0.f, a3 = 0.f;
  int i = r0;
  for (; i + 4 <= r1; i += 4) {
    int s0 = csr_src[i + 0], s1 = csr_src[i + 1];
    int s2 = csr_src[i + 2], s3 = csr_src[i + 3];
    int t0 = csr_et[i + 0], t1 = csr_et[i + 1];
    int t2 = csr_et[i + 2], t3 = csr_et[i + 3];
    a0 += trans[(size_t)(t0 * NN + s0) * DD + lane];
    a1 += trans[(size_t)(t1 * NN + s1) * DD + lane];
    a2 += trans[(size_t)(t2 * NN + s2) * DD + lane];
    a3 += trans[(size_t)(t3 * NN + s3) * DD + lane];
  }
  for (; i < r1; i++) {
    a0 += trans[(size_t)(csr_et[i] * NN + csr_src[i]) * DD + lane];
  }
  agg[(size_t)n * DD + lane] = (a0 + a1) + (a2 + a3);
}

// fused GRU cell: gi = agg@Wih^T+bih, gh = h@Whh^T+bhh (two LDS phases), update
__global__ __launch_bounds__(256) void k_gru(
    const float* __restrict__ agg, const float* __restrict__ h_in,
    const float* __restrict__ Wih, const float* __restrict__ bih,
    const float* __restrict__ Whh, const float* __restrict__ bhh,
    float* __restrict__ h_out) {
  __shared__ float w[192 * 65];
  int tid = threadIdx.x;
  int lane = tid & 63;
  int wid = tid >> 6;
  const int NPT = 4;
  int n0 = (blockIdx.x * 4 + wid) * NPT;  // grid 3125 * 16 = 50000 exact

  for (int i = tid; i < 192 * 64; i += 256) {
    int r = i >> 6, c = i & 63;
    w[r * 65 + c] = Wih[i];
  }
  __syncthreads();

  float ir[NPT], iz[NPT], ic[NPT];
#pragma unroll
  for (int g = 0; g < NPT; g++) { ir[g] = 0.f; iz[g] = 0.f; ic[g] = 0.f; }
#pragma unroll 4
  for (int d = 0; d < DD; d++) {
    float wr = w[lane * 65 + d];
    float wz = w[(64 + lane) * 65 + d];
    float wc = w[(128 + lane) * 65 + d];
#pragma unroll
    for (int g = 0; g < NPT; g++) {
      float a = agg[(size_t)(n0 + g) * DD + d];
      ir[g] = fmaf(a, wr, ir[g]);
      iz[g] = fmaf(a, wz, iz[g]);
      ic[g] = fmaf(a, wc, ic[g]);
    }
  }
  __syncthreads();
  for (int i = tid; i < 192 * 64; i += 256) {
    int r = i >> 6, c = i & 63;
    w[r * 65 + c] = Whh[i];
  }
  __syncthreads();

  float hr[NPT], hz[NPT], hc[NPT];
#pragma unroll
  for (int g = 0; g < NPT; g++) { hr[g] = 0.f; hz[g] = 0.f; hc[g] = 0.f; }
#pragma unroll 4
  for (int d = 0; d < DD; d++) {
    float wr = w[lane * 65 + d];
    float wz = w[(64 + lane) * 65 + d];
    float wc = w[(128 + lane) * 65 + d];
#pragma unroll
    for (int g = 0; g < NPT; g++) {
      float h = h_in[(size_t)(n0 + g) * DD + d];
      hr[g] = fmaf(h, wr, hr[g]);
      hz[g] = fmaf(h, wz, hz[g]);
      hc[g] = fmaf(h, wc, hc[g]);
    }
  }

  float b_ir = bih[lane], b_iz = bih[64 + lane], b_ic = bih[128 + lane];
  float b_hr = bhh[lane], b_hz = bhh[64 + lane], b_hc = bhh[128 + lane];
#pragma unroll
  for (int g = 0; g < NPT; g++) {
    int n = n0 + g;
    float r = 1.f / (1.f + expf(-((ir[g] + b_ir) + (hr[g] + b_hr))));
    float z = 1.f / (1.f + expf(-((iz[g] + b_iz) + (hz[g] + b_hz))));
    float c = tanhf((ic[g] + b_ic) + r * (hc[g] + b_hc));
    float hprev = h_in[(size_t)n * DD + lane];
    h_out[(size_t)n * DD + lane] = (1.f - z) * c + z * hprev;
  }
}

// ---------------- launch ----------------

extern "C" void kernel_launch(void* const* d_in, const int* in_sizes, int n_in,
                              void* d_out, int out_size, void* d_ws, size_t ws_size,
                              hipStream_t stream) {
  const float* x = (const float*)d_in[0];
  const int* src = (const int*)d_in[1];
  const int* dst = (const int*)d_in[2];
  const int* etypes = (const int*)d_in[3];

  float* out = (float*)d_out;

  // ws layout (floats), with aliasing:
  //   el      NN*DD      (aliased: htmp during GGC phase)
  //   er      NN*DD
  //   trans   2*NN*DD    (aliased: score_csr head during GAT phase)
  //   agg     NN*DD
  // then ints: deg NN, cursor NN, rowstart NN+1, csr_src EF, csr_dst EF, csr_et EF
  float* el = (float*)d_ws;
  float* er = el + (size_t)NN * DD;
  float* trans = er + (size_t)NN * DD;
  float* score = trans;  // alias (GAT phase only)
  float* agg = trans + (size_t)2 * NN * DD;
  float* htmp = el;      // alias (GGC phase only)
  int* deg = (int*)(agg + (size_t)NN * DD);
  int* cursor = deg + NN;
  int* rowstart = cursor + NN;
  int* csr_src = rowstart + (NN + 1);
  int* csr_dst = csr_src + EF;
  int* csr_et = csr_dst + EF;

  // CSR (grouped by dst) rebuilt every call (ws is re-poisoned)
  k_zero<<<(2 * NN + 255) / 256, 256, 0, stream>>>(deg, 2 * NN);
  k_degree<<<(EF + 255) / 256, 256, 0, stream>>>(dst, deg);
  k_scan<<<1, 1024, 0, stream>>>(deg, rowstart);
  k_bucket<<<(EF + 255) / 256, 256, 0, stream>>>(src, dst, etypes, rowstart, cursor,
                                                 csr_src, csr_dst, csr_et);

  for (int l = 0; l < 2; l++) {
    int base = 4 + 11 * l;
    const float* Wsrc = (const float*)d_in[base + 0];
    const float* bsrc = (const float*)d_in[base + 1];
    const float* Wdst = (const float*)d_in[base + 2];
    const float* bdst = (const float*)d_in[base + 3];
    const float* attn = (const float*)d_in[base + 4];
    const float* gW   = (const float*)d_in[base + 5];
    const float* gb   = (const float*)d_in[base + 6];
    const float* Wih  = (const float*)d_in[base + 7];
    const float* bih  = (const float*)d_in[base + 8];
    const float* Whh  = (const float*)d_in[base + 9];
    const float* bhh  = (const float*)d_in[base + 10];

    const float* xin = (l == 0) ? x : (out + 1 * (size_t)NN * DD);
    float* emb_gat = out + (size_t)(2 * l) * NN * DD;
    float* emb_ggc = out + (size_t)(2 * l + 1) * NN * DD;

    // GATv2
    k_linear2<<<1563, 256, 0, stream>>>(xin, Wsrc, bsrc, Wdst, bdst, el, er);
    k_edge_score<<<(EF + 255) / 256, 256, 0, stream>>>(el, er, attn, csr_src, csr_dst, score);
    k_gat_agg<<<(NN + 3) / 4, 256, 0, stream>>>(el, score, rowstart, csr_src, emb_gat);

    // GGC step 1
    k_trans<<<1563, 256, 0, stream>>>(emb_gat, gW, gb, trans);
    k_ggc_agg<<<(NN + 3) / 4, 256, 0, stream>>>(trans, rowstart, csr_src, csr_et, agg);
    k_gru<<<3125, 256, 0, stream>>>(agg, emb_gat, Wih, bih, Whh, bhh, htmp);

    // GGC step 2
    k_trans<<<1563, 256, 0, stream>>>(htmp, gW, gb, trans);
    k_ggc_agg<<<(NN + 3) / 4, 256, 0, stream>>>(trans, rowstart, csr_src, csr_et, agg);
    k_gru<<<3125, 256, 0, stream>>>(agg, htmp, Wih, bih, Whh, bhh, emb_ggc);
  }
}

// Round 3
// 972.120 us; speedup vs baseline: 1.8431x; 1.0885x over previous
//
#include <hip/hip_runtime.h>
#include <math.h>

#define NN 50000
#define EE 800000
#define EF (EE + NN)
#define DD 64
#define NEG_SLOPE 0.2f
#define NTILES 3125  // NN / 16 exactly

typedef unsigned short ushort;
typedef __attribute__((ext_vector_type(8))) short short8;
typedef __attribute__((ext_vector_type(4))) float floatx4;
typedef __attribute__((ext_vector_type(4))) unsigned int uintx4;

union frag_u { uintx4 u; short8 s; };

__device__ __forceinline__ ushort f2bf(float f) {
  union { float f; unsigned u; } v; v.f = f;
  unsigned r = v.u + 0x7FFFu + ((v.u >> 16) & 1u);
  return (ushort)(r >> 16);
}
__device__ __forceinline__ float bf2f(ushort h) {
  union { unsigned u; float f; } v; v.u = ((unsigned)h) << 16;
  return v.f;
}

__device__ __forceinline__ int src_of(const int* __restrict__ src, int e) {
  return (e < EE) ? src[e] : (e - EE);
}
__device__ __forceinline__ int dst_of(const int* __restrict__ dst, int e) {
  return (e < EE) ? dst[e] : (e - EE);
}

// ---------------- CSR build ----------------

__global__ void k_zero(int* __restrict__ p, int n) {
  int i = blockIdx.x * blockDim.x + threadIdx.x;
  if (i < n) p[i] = 0;
}

__global__ void k_degree(const int* __restrict__ dst, int* __restrict__ deg) {
  int e = blockIdx.x * blockDim.x + threadIdx.x;
  if (e < EF) atomicAdd(&deg[dst_of(dst, e)], 1);
}

__global__ void k_scan(const int* __restrict__ deg, int* __restrict__ rowstart) {
  __shared__ int wsum[16];
  __shared__ int chunk_total;
  __shared__ int carry_s;
  int tid = threadIdx.x;
  int lane = tid & 63;
  int wid = tid >> 6;
  if (tid == 0) carry_s = 0;
  __syncthreads();
  for (int base = 0; base < NN; base += 1024) {
    int i = base + tid;
    int v = (i < NN) ? deg[i] : 0;
    int s = v;
#pragma unroll
    for (int off = 1; off < 64; off <<= 1) {
      int t = __shfl_up(s, off, 64);
      if (lane >= off) s += t;
    }
    if (lane == 63) wsum[wid] = s;
    __syncthreads();
    if (wid == 0) {
      int wv = (lane < 16) ? wsum[lane] : 0;
      int ws2 = wv;
#pragma unroll
      for (int off = 1; off < 16; off <<= 1) {
        int t = __shfl_up(ws2, off, 64);
        if (lane >= off) ws2 += t;
      }
      if (lane < 16) wsum[lane] = ws2 - wv;
      if (lane == 15) chunk_total = ws2;
    }
    __syncthreads();
    int excl = carry_s + wsum[wid] + (s - v);
    if (i < NN) rowstart[i] = excl;
    __syncthreads();
    if (tid == 0) carry_s += chunk_total;
    __syncthreads();
  }
  if (tid == 0) rowstart[NN] = carry_s;
}

// bucket edges by dst; pack src|etype<<16 (src < 2^16)
__global__ void k_bucket(const int* __restrict__ src, const int* __restrict__ dst,
                         const int* __restrict__ etypes,
                         const int* __restrict__ rowstart, int* __restrict__ cursor,
                         int* __restrict__ csr_se, int* __restrict__ csr_dst) {
  int e = blockIdx.x * blockDim.x + threadIdx.x;
  if (e < EF) {
    int d = dst_of(dst, e);
    int pos = atomicAdd(&cursor[d], 1);
    int i = rowstart[d] + pos;
    csr_se[i] = src_of(src, e) | (etypes[e] << 16);
    csr_dst[i] = d;
  }
}

// ---------------- split fp32 -> bf16 hi/lo ----------------

__global__ void k_split(const float* __restrict__ x, ushort* __restrict__ hi,
                        ushort* __restrict__ lo, int n) {
  int i = blockIdx.x * blockDim.x + threadIdx.x;
  if (i < n) {
    float v = x[i];
    ushort h = f2bf(v);
    hi[i] = h;
    lo[i] = f2bf(v - bf2f(h));
  }
}

// ---------------- MFMA matmul kernels (3-term split-bf16) ----------------

// el = x @ Wsrc^T + bsrc ; er = x @ Wdst^T + bdst   (one 16-node tile per wave)
__global__ __launch_bounds__(256) void k_linear2_mfma(
    const ushort* __restrict__ xhi, const ushort* __restrict__ xlo,
    const float* __restrict__ Wsrc, const float* __restrict__ bsrc,
    const float* __restrict__ Wdst, const float* __restrict__ bdst,
    float* __restrict__ el, float* __restrict__ er) {
  int lane = threadIdx.x & 63;
  int tile = blockIdx.x * 4 + (threadIdx.x >> 6);
  if (tile >= NTILES) return;
  int nloc = lane & 15, q = lane >> 4;

  short8 Bh[2][4][2], Bl[2][4][2];
#pragma unroll
  for (int mat = 0; mat < 2; mat++) {
    const float* W = (mat == 0) ? Wsrc : Wdst;
#pragma unroll
    for (int nt = 0; nt < 4; nt++) {
#pragma unroll
      for (int ks = 0; ks < 2; ks++) {
        const float* wrow = W + (nt * 16 + nloc) * DD + ks * 32 + q * 8;
#pragma unroll
        for (int j = 0; j < 8; j++) {
          float w = wrow[j];
          ushort h = f2bf(w);
          Bh[mat][nt][ks][j] = (short)h;
          Bl[mat][nt][ks][j] = (short)f2bf(w - bf2f(h));
        }
      }
    }
  }

  floatx4 acc[2][4];
#pragma unroll
  for (int m = 0; m < 2; m++)
#pragma unroll
    for (int nt = 0; nt < 4; nt++) acc[m][nt] = (floatx4)0.f;

#pragma unroll
  for (int ks = 0; ks < 2; ks++) {
    size_t aoff = (size_t)(tile * 16 + nloc) * DD + ks * 32 + q * 8;
    frag_u ah, al;
    ah.u = *(const uintx4*)(xhi + aoff);
    al.u = *(const uintx4*)(xlo + aoff);
#pragma unroll
    for (int nt = 0; nt < 4; nt++) {
#pragma unroll
      for (int m = 0; m < 2; m++) {
        acc[m][nt] = __builtin_amdgcn_mfma_f32_16x16x32_bf16(ah.s, Bh[m][nt][ks], acc[m][nt], 0, 0, 0);
        acc[m][nt] = __builtin_amdgcn_mfma_f32_16x16x32_bf16(ah.s, Bl[m][nt][ks], acc[m][nt], 0, 0, 0);
        acc[m][nt] = __builtin_amdgcn_mfma_f32_16x16x32_bf16(al.s, Bh[m][nt][ks], acc[m][nt], 0, 0, 0);
      }
    }
  }

#pragma unroll
  for (int nt = 0; nt < 4; nt++) {
    int col = nt * 16 + nloc;
    float b0 = bsrc[col], b1 = bdst[col];
#pragma unroll
    for (int r = 0; r < 4; r++) {
      int row = tile * 16 + q * 4 + r;
      el[(size_t)row * DD + col] = acc[0][nt][r] + b0;
      er[(size_t)row * DD + col] = acc[1][nt][r] + b1;
    }
  }
}

// trans[t] = h @ W[t]^T + b[t], t=0,1
__global__ __launch_bounds__(256) void k_trans_mfma(
    const ushort* __restrict__ hhi, const ushort* __restrict__ hlo,
    const float* __restrict__ W,   // (2,64,64)
    const float* __restrict__ b,   // (2,64)
    float* __restrict__ trans) {   // (2,NN,64)
  int lane = threadIdx.x & 63;
  int tile = blockIdx.x * 4 + (threadIdx.x >> 6);
  if (tile >= NTILES) return;
  int nloc = lane & 15, q = lane >> 4;

  short8 Bh[2][4][2], Bl[2][4][2];
#pragma unroll
  for (int mat = 0; mat < 2; mat++) {
#pragma unroll
    for (int nt = 0; nt < 4; nt++) {
#pragma unroll
      for (int ks = 0; ks < 2; ks++) {
        const float* wrow = W + mat * DD * DD + (nt * 16 + nloc) * DD + ks * 32 + q * 8;
#pragma unroll
        for (int j = 0; j < 8; j++) {
          float w = wrow[j];
          ushort h = f2bf(w);
          Bh[mat][nt][ks][j] = (short)h;
          Bl[mat][nt][ks][j] = (short)f2bf(w - bf2f(h));
        }
      }
    }
  }

  floatx4 acc[2][4];
#pragma unroll
  for (int m = 0; m < 2; m++)
#pragma unroll
    for (int nt = 0; nt < 4; nt++) acc[m][nt] = (floatx4)0.f;

#pragma unroll
  for (int ks = 0; ks < 2; ks++) {
    size_t aoff = (size_t)(tile * 16 + nloc) * DD + ks * 32 + q * 8;
    frag_u ah, al;
    ah.u = *(const uintx4*)(hhi + aoff);
    al.u = *(const uintx4*)(hlo + aoff);
#pragma unroll
    for (int nt = 0; nt < 4; nt++) {
#pragma unroll
      for (int m = 0; m < 2; m++) {
        acc[m][nt] = __builtin_amdgcn_mfma_f32_16x16x32_bf16(ah.s, Bh[m][nt][ks], acc[m][nt], 0, 0, 0);
        acc[m][nt] = __builtin_amdgcn_mfma_f32_16x16x32_bf16(ah.s, Bl[m][nt][ks], acc[m][nt], 0, 0, 0);
        acc[m][nt] = __builtin_amdgcn_mfma_f32_16x16x32_bf16(al.s, Bh[m][nt][ks], acc[m][nt], 0, 0, 0);
      }
    }
  }

#pragma unroll
  for (int nt = 0; nt < 4; nt++) {
    int col = nt * 16 + nloc;
    float b0 = b[col], b1 = b[DD + col];
#pragma unroll
    for (int r = 0; r < 4; r++) {
      int row = tile * 16 + q * 4 + r;
      trans[(size_t)row * DD + col] = acc[0][nt][r] + b0;
      trans[(size_t)(NN + row) * DD + col] = acc[1][nt][r] + b1;
    }
  }
}

// fused GRU: gi = agg@Wih^T+bih, gh = h@Whh^T+bhh (two LDS phases), update.
// Writes h fp32 + bf16 hi/lo companions.
__global__ __launch_bounds__(256) void k_gru_mfma(
    const ushort* __restrict__ ahi, const ushort* __restrict__ alo,
    const ushort* __restrict__ hhi, const ushort* __restrict__ hlo,
    const float* __restrict__ h_in,
    const float* __restrict__ Wih, const float* __restrict__ bih,
    const float* __restrict__ Whh, const float* __restrict__ bhh,
    float* __restrict__ h_out, ushort* __restrict__ ohi, ushort* __restrict__ olo) {
  __shared__ ushort swh[192 * 72];
  __shared__ ushort swl[192 * 72];
  int tid = threadIdx.x;
  int lane = tid & 63;
  int nloc = lane & 15, q = lane >> 4;
  int tile = blockIdx.x * 4 + (tid >> 6);
  bool active = tile < NTILES;

  for (int i = tid; i < 192 * 64; i += 256) {
    int n = i >> 6, k = i & 63;
    float w = Wih[i];
    ushort h = f2bf(w);
    swh[n * 72 + k] = h;
    swl[n * 72 + k] = f2bf(w - bf2f(h));
  }
  __syncthreads();

  floatx4 gi[12];
#pragma unroll
  for (int nt = 0; nt < 12; nt++) gi[nt] = (floatx4)0.f;
  if (active) {
#pragma unroll
    for (int ks = 0; ks < 2; ks++) {
      size_t aoff = (size_t)(tile * 16 + nloc) * DD + ks * 32 + q * 8;
      frag_u ah, al;
      ah.u = *(const uintx4*)(ahi + aoff);
      al.u = *(const uintx4*)(alo + aoff);
#pragma unroll
      for (int nt = 0; nt < 12; nt++) {
        int widx = (nt * 16 + nloc) * 72 + ks * 32 + q * 8;
        frag_u bh, bl;
        bh.u = *(const uintx4*)(swh + widx);
        bl.u = *(const uintx4*)(swl + widx);
        gi[nt] = __builtin_amdgcn_mfma_f32_16x16x32_bf16(ah.s, bh.s, gi[nt], 0, 0, 0);
        gi[nt] = __builtin_amdgcn_mfma_f32_16x16x32_bf16(ah.s, bl.s, gi[nt], 0, 0, 0);
        gi[nt] = __builtin_amdgcn_mfma_f32_16x16x32_bf16(al.s, bh.s, gi[nt], 0, 0, 0);
      }
    }
  }
  __syncthreads();
  for (int i = tid; i < 192 * 64; i += 256) {
    int n = i >> 6, k = i & 63;
    float w = Whh[i];
    ushort h = f2bf(w);
    swh[n * 72 + k] = h;
    swl[n * 72 + k] = f2bf(w - bf2f(h));
  }
  __syncthreads();

  floatx4 gh[12];
#pragma unroll
  for (int nt = 0; nt < 12; nt++) gh[nt] = (floatx4)0.f;
  if (!active) return;
#pragma unroll
  for (int ks = 0; ks < 2; ks++) {
    size_t aoff = (size_t)(tile * 16 + nloc) * DD + ks * 32 + q * 8;
    frag_u ah, al;
    ah.u = *(const uintx4*)(hhi + aoff);
    al.u = *(const uintx4*)(hlo + aoff);
#pragma unroll
    for (int nt = 0; nt < 12; nt++) {
      int widx = (nt * 16 + nloc) * 72 + ks * 32 + q * 8;
      frag_u bh, bl;
      bh.u = *(const uintx4*)(swh + widx);
      bl.u = *(const uintx4*)(swl + widx);
      gh[nt] = __builtin_amdgcn_mfma_f32_16x16x32_bf16(ah.s, bh.s, gh[nt], 0, 0, 0);
      gh[nt] = __builtin_amdgcn_mfma_f32_16x16x32_bf16(ah.s, bl.s, gh[nt], 0, 0, 0);
      gh[nt] = __builtin_amdgcn_mfma_f32_16x16x32_bf16(al.s, bh.s, gh[nt], 0, 0, 0);
    }
  }

#pragma unroll
  for (int nt = 0; nt < 4; nt++) {
    int col = nt * 16 + nloc;
    float bir = bih[col], biz = bih[64 + col], bic = bih[128 + col];
    float bhr = bhh[col], bhz = bhh[64 + col], bhc = bhh[128 + col];
#pragma unroll
    for (int r = 0; r < 4; r++) {
      int row = tile * 16 + q * 4 + r;
      float irv = gi[nt][r] + bir, izv = gi[nt + 4][r] + biz, icv = gi[nt + 8][r] + bic;
      float hrv = gh[nt][r] + bhr, hzv = gh[nt + 4][r] + bhz, hcv = gh[nt + 8][r] + bhc;
      float rr = 1.f / (1.f + expf(-(irv + hrv)));
      float zz = 1.f / (1.f + expf(-(izv + hzv)));
      float cc = tanhf(icv + rr * hcv);
      float hp = h_in[(size_t)row * DD + col];
      float hn = (1.f - zz) * cc + zz * hp;
      size_t o = (size_t)row * DD + col;
      h_out[o] = hn;
      ushort hh = f2bf(hn);
      ohi[o] = hh;
      olo[o] = f2bf(hn - bf2f(hh));
    }
  }
}

// ---------------- edge kernels (fp32, unchanged structure) ----------------

__global__ __launch_bounds__(256) void k_edge_score(
    const float* __restrict__ el, const float* __restrict__ er,
    const float* __restrict__ attn,
    const int* __restrict__ csr_se, const int* __restrict__ csr_dst,
    float* __restrict__ score_csr) {
  __shared__ float sattn[DD];
  int tid = threadIdx.x;
  if (tid < DD) sattn[tid] = attn[tid];
  __syncthreads();
  int i = blockIdx.x * 256 + tid;
  if (i >= EF) return;
  int s = csr_se[i] & 0xFFFF;
  int t = csr_dst[i];
  const float4* a4 = (const float4*)(el + (size_t)s * DD);
  const float4* b4 = (const float4*)(er + (size_t)t * DD);
  float acc = 0.f;
#pragma unroll 4
  for (int qq = 0; qq < 16; qq++) {
    float4 ea = a4[qq];
    float4 eb = b4[qq];
    float v;
    v = ea.x + eb.x; v = (v > 0.f) ? v : NEG_SLOPE * v; acc = fmaf(v, sattn[4 * qq + 0], acc);
    v = ea.y + eb.y; v = (v > 0.f) ? v : NEG_SLOPE * v; acc = fmaf(v, sattn[4 * qq + 1], acc);
    v = ea.z + eb.z; v = (v > 0.f) ? v : NEG_SLOPE * v; acc = fmaf(v, sattn[4 * qq + 2], acc);
    v = ea.w + eb.w; v = (v > 0.f) ? v : NEG_SLOPE * v; acc = fmaf(v, sattn[4 * qq + 3], acc);
  }
  score_csr[i] = acc;
}

// wave per node: softmax + weighted gather + elu; writes fp32 out + bf16 hi/lo
__global__ __launch_bounds__(256) void k_gat_agg(
    const float* __restrict__ el, float* __restrict__ score_csr,
    const int* __restrict__ rowstart, const int* __restrict__ csr_se,
    float* __restrict__ out, ushort* __restrict__ ohi, ushort* __restrict__ olo) {
  int lane = threadIdx.x & 63;
  int n = blockIdx.x * 4 + (threadIdx.x >> 6);
  if (n >= NN) return;
  int r0 = rowstart[n], r1 = rowstart[n + 1];
  float m = -INFINITY;
  for (int i = r0 + lane; i < r1; i += 64) m = fmaxf(m, score_csr[i]);
#pragma unroll
  for (int off = 32; off > 0; off >>= 1) m = fmaxf(m, __shfl_xor(m, off, 64));
  float den = 0.f;
  for (int i = r0 + lane; i < r1; i += 64) {
    float ex = __expf(score_csr[i] - m);
    den += ex;
    score_csr[i] = ex;
  }
#pragma unroll
  for (int off = 32; off > 0; off >>= 1) den += __shfl_xor(den, off, 64);
  float a0 = 0.f, a1 = 0.f, a2 = 0.f, a3 = 0.f;
  int i = r0;
  for (; i + 4 <= r1; i += 4) {
    int s0 = csr_se[i + 0] & 0xFFFF, s1 = csr_se[i + 1] & 0xFFFF;
    int s2 = csr_se[i + 2] & 0xFFFF, s3 = csr_se[i + 3] & 0xFFFF;
    float w0 = score_csr[i + 0], w1 = score_csr[i + 1];
    float w2 = score_csr[i + 2], w3 = score_csr[i + 3];
    a0 = fmaf(w0, el[(size_t)s0 * DD + lane], a0);
    a1 = fmaf(w1, el[(size_t)s1 * DD + lane], a1);
    a2 = fmaf(w2, el[(size_t)s2 * DD + lane], a2);
    a3 = fmaf(w3, el[(size_t)s3 * DD + lane], a3);
  }
  for (; i < r1; i++) {
    a0 = fmaf(score_csr[i], el[(size_t)(csr_se[i] & 0xFFFF) * DD + lane], a0);
  }
  float o = ((a0 + a1) + (a2 + a3)) / den;
  o = (o > 0.f) ? o : expm1f(o);
  size_t oo = (size_t)n * DD + lane;
  out[oo] = o;
  ushort h = f2bf(o);
  ohi[oo] = h;
  olo[oo] = f2bf(o - bf2f(h));
}

// wave per node: agg[n] = sum trans[etype, src]; writes bf16 hi/lo only
__global__ __launch_bounds__(256) void k_ggc_agg(
    const float* __restrict__ trans,
    const int* __restrict__ rowstart, const int* __restrict__ csr_se,
    ushort* __restrict__ ahi, ushort* __restrict__ alo) {
  int lane = threadIdx.x & 63;
  int n = blockIdx.x * 4 + (threadIdx.x >> 6);
  if (n >= NN) return;
  int r0 = rowstart[n], r1 = rowstart[n + 1];
  float a0 = 0.f, a1 = 0.f, a2 = 0.f, a3 = 0.f;
  int i = r0;
  for (; i + 4 <= r1; i += 4) {
    int se0 = csr_se[i + 0], se1 = csr_se[i + 1];
    int se2 = csr_se[i + 2], se3 = csr_se[i + 3];
    a0 += trans[(size_t)((se0 >> 16) * NN + (se0 & 0xFFFF)) * DD + lane];
    a1 += trans[(size_t)((se1 >> 16) * NN + (se1 & 0xFFFF)) * DD + lane];
    a2 += trans[(size_t)((se2 >> 16) * NN + (se2 & 0xFFFF)) * DD + lane];
    a3 += trans[(size_t)((se3 >> 16) * NN + (se3 & 0xFFFF)) * DD + lane];
  }
  for (; i < r1; i++) {
    int se = csr_se[i];
    a0 += trans[(size_t)((se >> 16) * NN + (se & 0xFFFF)) * DD + lane];
  }
  float v = (a0 + a1) + (a2 + a3);
  size_t oo = (size_t)n * DD + lane;
  ushort h = f2bf(v);
  ahi[oo] = h;
  alo[oo] = f2bf(v - bf2f(h));
}

// ---------------- launch ----------------

extern "C" void kernel_launch(void* const* d_in, const int* in_sizes, int n_in,
                              void* d_out, int out_size, void* d_ws, size_t ws_size,
                              hipStream_t stream) {
  const float* x = (const float*)d_in[0];
  const int* src = (const int*)d_in[1];
  const int* dst = (const int*)d_in[2];
  const int* etypes = (const int*)d_in[3];

  float* out = (float*)d_out;

  // ws layout:
  //  floats: el (NN*DD) [alias htmp], er (NN*DD) [alias agg hi/lo pair],
  //          trans (2*NN*DD) [alias score head]
  //  ushort: pairA hi/lo (gat emb / next-layer input), pairB hi/lo (x split / gru h)
  //  ints:   deg, cursor, rowstart, csr_se, csr_dst
  float* el = (float*)d_ws;
  float* er = el + (size_t)NN * DD;
  float* trans = er + (size_t)NN * DD;
  float* score = trans;                 // alias (GAT phase)
  float* htmp = el;                     // alias (GGC phase)
  ushort* agg_hi = (ushort*)er;         // alias (GGC phase)
  ushort* agg_lo = agg_hi + (size_t)NN * DD;
  ushort* pA_hi = (ushort*)(trans + (size_t)2 * NN * DD);
  ushort* pA_lo = pA_hi + (size_t)NN * DD;
  ushort* pB_hi = pA_lo + (size_t)NN * DD;
  ushort* pB_lo = pB_hi + (size_t)NN * DD;
  int* deg = (int*)(pB_lo + (size_t)NN * DD);
  int* cursor = deg + NN;
  int* rowstart = cursor + NN;
  int* csr_se = rowstart + (NN + 1);
  int* csr_dst = csr_se + EF;

  k_zero<<<(2 * NN + 255) / 256, 256, 0, stream>>>(deg, 2 * NN);
  k_degree<<<(EF + 255) / 256, 256, 0, stream>>>(dst, deg);
  k_scan<<<1, 1024, 0, stream>>>(deg, rowstart);
  k_bucket<<<(EF + 255) / 256, 256, 0, stream>>>(src, dst, etypes, rowstart, cursor,
                                                 csr_se, csr_dst);
  k_split<<<(NN * DD + 255) / 256, 256, 0, stream>>>(x, pB_hi, pB_lo, NN * DD);

  const int MMBLK = (NTILES + 3) / 4;  // 782 blocks, 4 waves (tiles) each

  for (int l = 0; l < 2; l++) {
    int base = 4 + 11 * l;
    const float* Wsrc = (const float*)d_in[base + 0];
    const float* bsrc = (const float*)d_in[base + 1];
    const float* Wdst = (const float*)d_in[base + 2];
    const float* bdst = (const float*)d_in[base + 3];
    const float* attn = (const float*)d_in[base + 4];
    const float* gW   = (const float*)d_in[base + 5];
    const float* gb   = (const float*)d_in[base + 6];
    const float* Wih  = (const float*)d_in[base + 7];
    const float* bih  = (const float*)d_in[base + 8];
    const float* Whh  = (const float*)d_in[base + 9];
    const float* bhh  = (const float*)d_in[base + 10];

    const ushort* in_hi = (l == 0) ? pB_hi : pA_hi;
    const ushort* in_lo = (l == 0) ? pB_lo : pA_lo;
    float* emb_gat = out + (size_t)(2 * l) * NN * DD;
    float* emb_ggc = out + (size_t)(2 * l + 1) * NN * DD;

    // GATv2
    k_linear2_mfma<<<MMBLK, 256, 0, stream>>>(in_hi, in_lo, Wsrc, bsrc, Wdst, bdst, el, er);
    k_edge_score<<<(EF + 255) / 256, 256, 0, stream>>>(el, er, attn, csr_se, csr_dst, score);
    k_gat_agg<<<(NN + 3) / 4, 256, 0, stream>>>(el, score, rowstart, csr_se,
                                                emb_gat, pA_hi, pA_lo);

    // GGC step 1 (h = emb_gat, pair = pA)
    k_trans_mfma<<<MMBLK, 256, 0, stream>>>(pA_hi, pA_lo, gW, gb, trans);
    k_ggc_agg<<<(NN + 3) / 4, 256, 0, stream>>>(trans, rowstart, csr_se, agg_hi, agg_lo);
    k_gru_mfma<<<MMBLK, 256, 0, stream>>>(agg_hi, agg_lo, pA_hi, pA_lo, emb_gat,
                                          Wih, bih, Whh, bhh, htmp, pB_hi, pB_lo);

    // GGC step 2 (h = htmp, pair = pB); output pair -> pA (next layer input)
    k_trans_mfma<<<MMBLK, 256, 0, stream>>>(pB_hi, pB_lo, gW, gb, trans);
    k_ggc_agg<<<(NN + 3) / 4, 256, 0, stream>>>(trans, rowstart, csr_se, agg_hi, agg_lo);
    k_gru_mfma<<<MMBLK, 256, 0, stream>>>(agg_hi, agg_lo, pB_hi, pB_lo, htmp,
                                          Wih, bih, Whh, bhh, emb_ggc, pA_hi, pA_lo);
  }
}

// Round 4
// 940.032 us; speedup vs baseline: 1.9060x; 1.0341x over previous
//
#include <hip/hip_runtime.h>
#include <math.h>

#define NN 50000
#define EE 800000
#define EF (EE + NN)
#define DD 64
#define NEG_SLOPE 0.2f
#define NT16 3125   // NN/16 exactly
#define NT32 1563   // ceil(NN/32)

// per-layer split-weight region (ushort elems): wsrc 4096 | wdst 4096 | gw 8192 | wfuse 192*128
#define WL_WSRC 0
#define WL_WDST 4096
#define WL_GW   8192
#define WL_WFUSE 16384
#define WL_TOTAL 40960

typedef unsigned short ushort;
typedef __attribute__((ext_vector_type(8))) short short8;
typedef __attribute__((ext_vector_type(4))) float floatx4;
typedef __attribute__((ext_vector_type(4))) unsigned int uintx4;

union frag_u { uintx4 u; short8 s; };

__device__ __forceinline__ ushort f2bf(float f) {
  union { float f; unsigned u; } v; v.f = f;
  unsigned r = v.u + 0x7FFFu + ((v.u >> 16) & 1u);
  return (ushort)(r >> 16);
}
__device__ __forceinline__ float bf2f(ushort h) {
  union { unsigned u; float f; } v; v.u = ((unsigned)h) << 16;
  return v.f;
}

__device__ __forceinline__ int src_of(const int* __restrict__ src, int e) {
  return (e < EE) ? src[e] : (e - EE);
}
__device__ __forceinline__ int dst_of(const int* __restrict__ dst, int e) {
  return (e < EE) ? dst[e] : (e - EE);
}

// ---------------- CSR build ----------------

__global__ void k_zero(int* __restrict__ p, int n) {
  int i = blockIdx.x * blockDim.x + threadIdx.x;
  if (i < n) p[i] = 0;
}

__global__ void k_degree(const int* __restrict__ dst, int* __restrict__ deg) {
  int e = blockIdx.x * blockDim.x + threadIdx.x;
  if (e < EF) atomicAdd(&deg[dst_of(dst, e)], 1);
}

__global__ void k_scan(const int* __restrict__ deg, int* __restrict__ rowstart) {
  __shared__ int wsum[16];
  __shared__ int chunk_total;
  __shared__ int carry_s;
  int tid = threadIdx.x;
  int lane = tid & 63;
  int wid = tid >> 6;
  if (tid == 0) carry_s = 0;
  __syncthreads();
  for (int base = 0; base < NN; base += 1024) {
    int i = base + tid;
    int v = (i < NN) ? deg[i] : 0;
    int s = v;
#pragma unroll
    for (int off = 1; off < 64; off <<= 1) {
      int t = __shfl_up(s, off, 64);
      if (lane >= off) s += t;
    }
    if (lane == 63) wsum[wid] = s;
    __syncthreads();
    if (wid == 0) {
      int wv = (lane < 16) ? wsum[lane] : 0;
      int ws2 = wv;
#pragma unroll
      for (int off = 1; off < 16; off <<= 1) {
        int t = __shfl_up(ws2, off, 64);
        if (lane >= off) ws2 += t;
      }
      if (lane < 16) wsum[lane] = ws2 - wv;
      if (lane == 15) chunk_total = ws2;
    }
    __syncthreads();
    int excl = carry_s + wsum[wid] + (s - v);
    if (i < NN) rowstart[i] = excl;
    __syncthreads();
    if (tid == 0) carry_s += chunk_total;
    __syncthreads();
  }
  if (tid == 0) rowstart[NN] = carry_s;
}

__global__ void k_bucket(const int* __restrict__ src, const int* __restrict__ dst,
                         const int* __restrict__ etypes,
                         const int* __restrict__ rowstart, int* __restrict__ cursor,
                         int* __restrict__ csr_se, int* __restrict__ csr_dst) {
  int e = blockIdx.x * blockDim.x + threadIdx.x;
  if (e < EF) {
    int d = dst_of(dst, e);
    int pos = atomicAdd(&cursor[d], 1);
    int i = rowstart[d] + pos;
    csr_se[i] = src_of(src, e) | (etypes[e] << 16);
    csr_dst[i] = d;
  }
}

// ---------------- splits ----------------

__global__ void k_split(const float* __restrict__ x, ushort* __restrict__ hi,
                        ushort* __restrict__ lo, int n) {
  int i = blockIdx.x * blockDim.x + threadIdx.x;
  if (i < n) {
    float v = x[i];
    ushort h = f2bf(v);
    hi[i] = h;
    lo[i] = f2bf(v - bf2f(h));
  }
}

// one layer's weights -> hi/lo split region (B-frag-ready layouts)
__global__ void k_split_w(const float* __restrict__ Wsrc, const float* __restrict__ Wdst,
                          const float* __restrict__ gW, const float* __restrict__ Wih,
                          const float* __restrict__ Whh,
                          ushort* __restrict__ whi, ushort* __restrict__ wlo) {
  int i = blockIdx.x * blockDim.x + threadIdx.x;
  if (i >= WL_TOTAL) return;
  float v;
  if (i < WL_WDST) v = Wsrc[i];
  else if (i < WL_GW) v = Wdst[i - WL_WDST];
  else if (i < WL_WFUSE) v = gW[i - WL_GW];
  else {
    int f = i - WL_WFUSE;
    int c = f >> 7, k = f & 127;
    v = (k < 64) ? Wih[c * 64 + k] : Whh[c * 64 + (k - 64)];
  }
  ushort h = f2bf(v);
  whi[i] = h;
  wlo[i] = f2bf(v - bf2f(h));
}

// ---------------- MFMA matmuls (register-B, no LDS) ----------------

// el = x@Wsrc^T+bsrc ; er = x@Wdst^T+bdst. M=32 per wave.
__global__ __launch_bounds__(256) void k_linear2_mfma(
    const ushort* __restrict__ xhi, const ushort* __restrict__ xlo,
    const ushort* __restrict__ whi, const ushort* __restrict__ wlo,
    const float* __restrict__ bsrc, const float* __restrict__ bdst,
    float* __restrict__ el, float* __restrict__ er) {
  int lane = threadIdx.x & 63;
  int wv = blockIdx.x * 4 + (threadIdx.x >> 6);
  if (wv >= NT32) return;
  int nloc = lane & 15, q = lane >> 4;
  int n0 = wv * 32;

  floatx4 acc[2][2][4];  // [mt][mat][nt]
#pragma unroll
  for (int a = 0; a < 2; a++)
#pragma unroll
    for (int b = 0; b < 2; b++)
#pragma unroll
      for (int c = 0; c < 4; c++) acc[a][b][c] = (floatx4)0.f;

#pragma unroll
  for (int ks = 0; ks < 2; ks++) {
    frag_u ah[2], al[2];
#pragma unroll
    for (int mt = 0; mt < 2; mt++) {
      size_t aoff = (size_t)(n0 + mt * 16 + nloc) * DD + ks * 32 + q * 8;
      ah[mt].u = *(const uintx4*)(xhi + aoff);
      al[mt].u = *(const uintx4*)(xlo + aoff);
    }
#pragma unroll
    for (int mat = 0; mat < 2; mat++) {
#pragma unroll
      for (int nt = 0; nt < 4; nt++) {
        size_t boff = (size_t)(mat ? WL_WDST : WL_WSRC) + (nt * 16 + nloc) * DD + ks * 32 + q * 8;
        frag_u bh, bl;
        bh.u = *(const uintx4*)(whi + boff);
        bl.u = *(const uintx4*)(wlo + boff);
#pragma unroll
        for (int mt = 0; mt < 2; mt++) {
          acc[mt][mat][nt] = __builtin_amdgcn_mfma_f32_16x16x32_bf16(ah[mt].s, bh.s, acc[mt][mat][nt], 0, 0, 0);
          acc[mt][mat][nt] = __builtin_amdgcn_mfma_f32_16x16x32_bf16(ah[mt].s, bl.s, acc[mt][mat][nt], 0, 0, 0);
          acc[mt][mat][nt] = __builtin_amdgcn_mfma_f32_16x16x32_bf16(al[mt].s, bh.s, acc[mt][mat][nt], 0, 0, 0);
        }
      }
    }
  }

#pragma unroll
  for (int nt = 0; nt < 4; nt++) {
    int col = nt * 16 + nloc;
    float b0 = bsrc[col], b1 = bdst[col];
#pragma unroll
    for (int mt = 0; mt < 2; mt++) {
#pragma unroll
      for (int r = 0; r < 4; r++) {
        int row = n0 + mt * 16 + q * 4 + r;
        if (row < NN) {
          el[(size_t)row * DD + col] = acc[mt][0][nt][r] + b0;
          er[(size_t)row * DD + col] = acc[mt][1][nt][r] + b1;
        }
      }
    }
  }
}

// trans[t] = h@W[t]^T + b[t]. M=32 per wave.
__global__ __launch_bounds__(256) void k_trans_mfma(
    const ushort* __restrict__ hhi, const ushort* __restrict__ hlo,
    const ushort* __restrict__ whi, const ushort* __restrict__ wlo,
    const float* __restrict__ b,
    float* __restrict__ trans) {
  int lane = threadIdx.x & 63;
  int wv = blockIdx.x * 4 + (threadIdx.x >> 6);
  if (wv >= NT32) return;
  int nloc = lane & 15, q = lane >> 4;
  int n0 = wv * 32;

  floatx4 acc[2][2][4];
#pragma unroll
  for (int a = 0; a < 2; a++)
#pragma unroll
    for (int bb = 0; bb < 2; bb++)
#pragma unroll
      for (int c = 0; c < 4; c++) acc[a][bb][c] = (floatx4)0.f;

#pragma unroll
  for (int ks = 0; ks < 2; ks++) {
    frag_u ah[2], al[2];
#pragma unroll
    for (int mt = 0; mt < 2; mt++) {
      size_t aoff = (size_t)(n0 + mt * 16 + nloc) * DD + ks * 32 + q * 8;
      ah[mt].u = *(const uintx4*)(hhi + aoff);
      al[mt].u = *(const uintx4*)(hlo + aoff);
    }
#pragma unroll
    for (int mat = 0; mat < 2; mat++) {
#pragma unroll
      for (int nt = 0; nt < 4; nt++) {
        size_t boff = (size_t)WL_GW + mat * 4096 + (nt * 16 + nloc) * DD + ks * 32 + q * 8;
        frag_u bh, bl;
        bh.u = *(const uintx4*)(whi + boff);
        bl.u = *(const uintx4*)(wlo + boff);
#pragma unroll
        for (int mt = 0; mt < 2; mt++) {
          acc[mt][mat][nt] = __builtin_amdgcn_mfma_f32_16x16x32_bf16(ah[mt].s, bh.s, acc[mt][mat][nt], 0, 0, 0);
          acc[mt][mat][nt] = __builtin_amdgcn_mfma_f32_16x16x32_bf16(ah[mt].s, bl.s, acc[mt][mat][nt], 0, 0, 0);
          acc[mt][mat][nt] = __builtin_amdgcn_mfma_f32_16x16x32_bf16(al[mt].s, bh.s, acc[mt][mat][nt], 0, 0, 0);
        }
      }
    }
  }

#pragma unroll
  for (int nt = 0; nt < 4; nt++) {
    int col = nt * 16 + nloc;
    float b0 = b[col], b1 = b[DD + col];
#pragma unroll
    for (int mt = 0; mt < 2; mt++) {
#pragma unroll
      for (int r = 0; r < 4; r++) {
        int row = n0 + mt * 16 + q * 4 + r;
        if (row < NN) {
          trans[(size_t)row * DD + col] = acc[mt][0][nt][r] + b0;
          trans[(size_t)(NN + row) * DD + col] = acc[mt][1][nt][r] + b1;
        }
      }
    }
  }
}

// fused GRU: K=128 concat [Wih|Whh] per gate col; A = agg (ks 0-1), h (ks 2-3).
// r,z gates fully fused; c gate keeps ic/hc separate. M=16 per wave, no LDS.
__global__ __launch_bounds__(256) void k_gru_mfma(
    const ushort* __restrict__ ahi, const ushort* __restrict__ alo,
    const ushort* __restrict__ hhi, const ushort* __restrict__ hlo,
    const float* __restrict__ h_in,
    const ushort* __restrict__ whi, const ushort* __restrict__ wlo,  // wfuse region
    const float* __restrict__ bih, const float* __restrict__ bhh,
    float* __restrict__ h_out, ushort* __restrict__ ohi, ushort* __restrict__ olo) {
  int lane = threadIdx.x & 63;
  int tile = blockIdx.x * 4 + (threadIdx.x >> 6);
  if (tile >= NT16) return;
  int nloc = lane & 15, q = lane >> 4;
  const ushort* wfh = whi + WL_WFUSE;
  const ushort* wfl = wlo + WL_WFUSE;

  floatx4 ar[4], az[4], aic[4], ahc[4];
#pragma unroll
  for (int nt = 0; nt < 4; nt++) {
    ar[nt] = (floatx4)0.f; az[nt] = (floatx4)0.f;
    aic[nt] = (floatx4)0.f; ahc[nt] = (floatx4)0.f;
  }

#pragma unroll
  for (int ks = 0; ks < 4; ks++) {
    const ushort* Ahi = (ks < 2) ? ahi : hhi;
    const ushort* Alo = (ks < 2) ? alo : hlo;
    size_t aoff = (size_t)(tile * 16 + nloc) * DD + (ks & 1) * 32 + q * 8;
    frag_u fah, fal;
    fah.u = *(const uintx4*)(Ahi + aoff);
    fal.u = *(const uintx4*)(Alo + aoff);
#pragma unroll
    for (int g = 0; g < 3; g++) {  // gate group: r, z, c
#pragma unroll
      for (int nt = 0; nt < 4; nt++) {
        int col = g * 64 + nt * 16 + nloc;
        size_t boff = (size_t)col * 128 + ks * 32 + q * 8;
        frag_u bh, bl;
        bh.u = *(const uintx4*)(wfh + boff);
        bl.u = *(const uintx4*)(wfl + boff);
        floatx4* acc = (g == 0) ? &ar[nt] : (g == 1) ? &az[nt] : ((ks < 2) ? &aic[nt] : &ahc[nt]);
        *acc = __builtin_amdgcn_mfma_f32_16x16x32_bf16(fah.s, bh.s, *acc, 0, 0, 0);
        *acc = __builtin_amdgcn_mfma_f32_16x16x32_bf16(fah.s, bl.s, *acc, 0, 0, 0);
        *acc = __builtin_amdgcn_mfma_f32_16x16x32_bf16(fal.s, bh.s, *acc, 0, 0, 0);
      }
    }
  }

#pragma unroll
  for (int nt = 0; nt < 4; nt++) {
    int col = nt * 16 + nloc;
    float br = bih[col] + bhh[col];
    float bz = bih[64 + col] + bhh[64 + col];
    float bic = bih[128 + col], bhc = bhh[128 + col];
#pragma unroll
    for (int r = 0; r < 4; r++) {
      int row = tile * 16 + q * 4 + r;
      float rr = 1.f / (1.f + expf(-(ar[nt][r] + br)));
      float zz = 1.f / (1.f + expf(-(az[nt][r] + bz)));
      float cc = tanhf((aic[nt][r] + bic) + rr * (ahc[nt][r] + bhc));
      float hp = h_in[(size_t)row * DD + col];
      float hn = (1.f - zz) * cc + zz * hp;
      size_t o = (size_t)row * DD + col;
      h_out[o] = hn;
      ushort hh = f2bf(hn);
      ohi[o] = hh;
      olo[o] = f2bf(hn - bf2f(hh));
    }
  }
}

// ---------------- edge kernels ----------------

__global__ __launch_bounds__(256) void k_edge_score(
    const float* __restrict__ el, const float* __restrict__ er,
    const float* __restrict__ attn,
    const int* __restrict__ csr_se, const int* __restrict__ csr_dst,
    float* __restrict__ score_csr) {
  __shared__ float sattn[DD];
  int tid = threadIdx.x;
  if (tid < DD) sattn[tid] = attn[tid];
  __syncthreads();
  int i = blockIdx.x * 256 + tid;
  if (i >= EF) return;
  int s = csr_se[i] & 0xFFFF;
  int t = csr_dst[i];
  const float4* a4 = (const float4*)(el + (size_t)s * DD);
  const float4* b4 = (const float4*)(er + (size_t)t * DD);
  float acc = 0.f;
#pragma unroll 4
  for (int qq = 0; qq < 16; qq++) {
    float4 ea = a4[qq];
    float4 eb = b4[qq];
    float v;
    v = ea.x + eb.x; v = (v > 0.f) ? v : NEG_SLOPE * v; acc = fmaf(v, sattn[4 * qq + 0], acc);
    v = ea.y + eb.y; v = (v > 0.f) ? v : NEG_SLOPE * v; acc = fmaf(v, sattn[4 * qq + 1], acc);
    v = ea.z + eb.z; v = (v > 0.f) ? v : NEG_SLOPE * v; acc = fmaf(v, sattn[4 * qq + 2], acc);
    v = ea.w + eb.w; v = (v > 0.f) ? v : NEG_SLOPE * v; acc = fmaf(v, sattn[4 * qq + 3], acc);
  }
  score_csr[i] = acc;
}

__global__ __launch_bounds__(256) void k_gat_agg(
    const float* __restrict__ el, float* __restrict__ score_csr,
    const int* __restrict__ rowstart, const int* __restrict__ csr_se,
    float* __restrict__ out, ushort* __restrict__ ohi, ushort* __restrict__ olo) {
  int lane = threadIdx.x & 63;
  int n = blockIdx.x * 4 + (threadIdx.x >> 6);
  if (n >= NN) return;
  int r0 = rowstart[n], r1 = rowstart[n + 1];
  float m = -INFINITY;
  for (int i = r0 + lane; i < r1; i += 64) m = fmaxf(m, score_csr[i]);
#pragma unroll
  for (int off = 32; off > 0; off >>= 1) m = fmaxf(m, __shfl_xor(m, off, 64));
  float den = 0.f;
  for (int i = r0 + lane; i < r1; i += 64) {
    float ex = __expf(score_csr[i] - m);
    den += ex;
    score_csr[i] = ex;
  }
#pragma unroll
  for (int off = 32; off > 0; off >>= 1) den += __shfl_xor(den, off, 64);
  float a0 = 0.f, a1 = 0.f, a2 = 0.f, a3 = 0.f;
  int i = r0;
  for (; i + 4 <= r1; i += 4) {
    int s0 = csr_se[i + 0] & 0xFFFF, s1 = csr_se[i + 1] & 0xFFFF;
    int s2 = csr_se[i + 2] & 0xFFFF, s3 = csr_se[i + 3] & 0xFFFF;
    float w0 = score_csr[i + 0], w1 = score_csr[i + 1];
    float w2 = score_csr[i + 2], w3 = score_csr[i + 3];
    a0 = fmaf(w0, el[(size_t)s0 * DD + lane], a0);
    a1 = fmaf(w1, el[(size_t)s1 * DD + lane], a1);
    a2 = fmaf(w2, el[(size_t)s2 * DD + lane], a2);
    a3 = fmaf(w3, el[(size_t)s3 * DD + lane], a3);
  }
  for (; i < r1; i++) {
    a0 = fmaf(score_csr[i], el[(size_t)(csr_se[i] & 0xFFFF) * DD + lane], a0);
  }
  float o = ((a0 + a1) + (a2 + a3)) / den;
  o = (o > 0.f) ? o : expm1f(o);
  size_t oo = (size_t)n * DD + lane;
  out[oo] = o;
  ushort h = f2bf(o);
  ohi[oo] = h;
  olo[oo] = f2bf(o - bf2f(h));
}

__global__ __launch_bounds__(256) void k_ggc_agg(
    const float* __restrict__ trans,
    const int* __restrict__ rowstart, const int* __restrict__ csr_se,
    ushort* __restrict__ ahi, ushort* __restrict__ alo) {
  int lane = threadIdx.x & 63;
  int n = blockIdx.x * 4 + (threadIdx.x >> 6);
  if (n >= NN) return;
  int r0 = rowstart[n], r1 = rowstart[n + 1];
  float a0 = 0.f, a1 = 0.f, a2 = 0.f, a3 = 0.f;
  int i = r0;
  for (; i + 4 <= r1; i += 4) {
    int se0 = csr_se[i + 0], se1 = csr_se[i + 1];
    int se2 = csr_se[i + 2], se3 = csr_se[i + 3];
    a0 += trans[(size_t)((se0 >> 16) * NN + (se0 & 0xFFFF)) * DD + lane];
    a1 += trans[(size_t)((se1 >> 16) * NN + (se1 & 0xFFFF)) * DD + lane];
    a2 += trans[(size_t)((se2 >> 16) * NN + (se2 & 0xFFFF)) * DD + lane];
    a3 += trans[(size_t)((se3 >> 16) * NN + (se3 & 0xFFFF)) * DD + lane];
  }
  for (; i < r1; i++) {
    int se = csr_se[i];
    a0 += trans[(size_t)((se >> 16) * NN + (se & 0xFFFF)) * DD + lane];
  }
  float v = (a0 + a1) + (a2 + a3);
  size_t oo = (size_t)n * DD + lane;
  ushort h = f2bf(v);
  ahi[oo] = h;
  alo[oo] = f2bf(v - bf2f(h));
}

// ---------------- launch ----------------

extern "C" void kernel_launch(void* const* d_in, const int* in_sizes, int n_in,
                              void* d_out, int out_size, void* d_ws, size_t ws_size,
                              hipStream_t stream) {
  const float* x = (const float*)d_in[0];
  const int* src = (const int*)d_in[1];
  const int* dst = (const int*)d_in[2];
  const int* etypes = (const int*)d_in[3];

  float* out = (float*)d_out;

  float* el = (float*)d_ws;
  float* er = el + (size_t)NN * DD;
  float* trans = er + (size_t)NN * DD;
  float* score = trans;                 // alias (GAT phase)
  float* htmp = el;                     // alias (GGC phase)
  ushort* agg_hi = (ushort*)er;         // alias (GGC phase)
  ushort* agg_lo = agg_hi + (size_t)NN * DD;
  ushort* pA_hi = (ushort*)(trans + (size_t)2 * NN * DD);
  ushort* pA_lo = pA_hi + (size_t)NN * DD;
  ushort* pB_hi = pA_lo + (size_t)NN * DD;
  ushort* pB_lo = pB_hi + (size_t)NN * DD;
  ushort* whi = pB_lo + (size_t)NN * DD;   // 2 layers x WL_TOTAL
  ushort* wlo = whi + 2 * WL_TOTAL;
  int* deg = (int*)(wlo + 2 * WL_TOTAL);
  int* cursor = deg + NN;
  int* rowstart = cursor + NN;
  int* csr_se = rowstart + (NN + 1);
  int* csr_dst = csr_se + EF;

  k_zero<<<(2 * NN + 255) / 256, 256, 0, stream>>>(deg, 2 * NN);
  k_degree<<<(EF + 255) / 256, 256, 0, stream>>>(dst, deg);
  k_scan<<<1, 1024, 0, stream>>>(deg, rowstart);
  k_bucket<<<(EF + 255) / 256, 256, 0, stream>>>(src, dst, etypes, rowstart, cursor,
                                                 csr_se, csr_dst);
  k_split<<<(NN * DD + 255) / 256, 256, 0, stream>>>(x, pB_hi, pB_lo, NN * DD);
  for (int l = 0; l < 2; l++) {
    int base = 4 + 11 * l;
    k_split_w<<<(WL_TOTAL + 255) / 256, 256, 0, stream>>>(
        (const float*)d_in[base + 0], (const float*)d_in[base + 2],
        (const float*)d_in[base + 5], (const float*)d_in[base + 7],
        (const float*)d_in[base + 9], whi + l * WL_TOTAL, wlo + l * WL_TOTAL);
  }

  const int B32 = (NT32 + 3) / 4;  // 391
  const int B16 = (NT16 + 3) / 4;  // 782

  for (int l = 0; l < 2; l++) {
    int base = 4 + 11 * l;
    const float* bsrc = (const float*)d_in[base + 1];
    const float* bdst = (const float*)d_in[base + 3];
    const float* attn = (const float*)d_in[base + 4];
    const float* gb   = (const float*)d_in[base + 6];
    const float* bih  = (const float*)d_in[base + 8];
    const float* bhh  = (const float*)d_in[base + 10];
    const ushort* lwhi = whi + l * WL_TOTAL;
    const ushort* lwlo = wlo + l * WL_TOTAL;

    const ushort* in_hi = (l == 0) ? pB_hi : pA_hi;
    const ushort* in_lo = (l == 0) ? pB_lo : pA_lo;
    float* emb_gat = out + (size_t)(2 * l) * NN * DD;
    float* emb_ggc = out + (size_t)(2 * l + 1) * NN * DD;

    // GATv2
    k_linear2_mfma<<<B32, 256, 0, stream>>>(in_hi, in_lo, lwhi, lwlo, bsrc, bdst, el, er);
    k_edge_score<<<(EF + 255) / 256, 256, 0, stream>>>(el, er, attn, csr_se, csr_dst, score);
    k_gat_agg<<<(NN + 3) / 4, 256, 0, stream>>>(el, score, rowstart, csr_se,
                                                emb_gat, pA_hi, pA_lo);

    // GGC step 1 (h = emb_gat, pair = pA)
    k_trans_mfma<<<B32, 256, 0, stream>>>(pA_hi, pA_lo, lwhi, lwlo, gb, trans);
    k_ggc_agg<<<(NN + 3) / 4, 256, 0, stream>>>(trans, rowstart, csr_se, agg_hi, agg_lo);
    k_gru_mfma<<<B16, 256, 0, stream>>>(agg_hi, agg_lo, pA_hi, pA_lo, emb_gat,
                                        lwhi, lwlo, bih, bhh, htmp, pB_hi, pB_lo);

    // GGC step 2 (h = htmp, pair = pB); output pair -> pA (next layer input)
    k_trans_mfma<<<B32, 256, 0, stream>>>(pB_hi, pB_lo, lwhi, lwlo, gb, trans);
    k_ggc_agg<<<(NN + 3) / 4, 256, 0, stream>>>(trans, rowstart, csr_se, agg_hi, agg_lo);
    k_gru_mfma<<<B16, 256, 0, stream>>>(agg_hi, agg_lo, pB_hi, pB_lo, htmp,
                                        lwhi, lwlo, bih, bhh, emb_ggc, pA_hi, pA_lo);
  }
}

// Round 5
// 932.537 us; speedup vs baseline: 1.9213x; 1.0080x over previous
//
#include <hip/hip_runtime.h>
#include <math.h>

#define NN 50000
#define EE 800000
#define EF (EE + NN)
#define DD 64
#define NEG_SLOPE 0.2f
#define NT16 3125   // NN/16 exactly

// per-layer split-weight region (ushort elems): wsrc 4096 | wdst 4096 | WF 192*192
#define WL_WDST 4096
#define WL_WF   8192
#define WL_TOTAL (8192 + 192 * 192)   // 45056

typedef unsigned short ushort;
typedef __attribute__((ext_vector_type(8))) short short8;
typedef __attribute__((ext_vector_type(4))) float floatx4;
typedef __attribute__((ext_vector_type(4))) unsigned int uintx4;

union frag_u { uintx4 u; short8 s; };

__device__ __forceinline__ ushort f2bf(float f) {
  union { float f; unsigned u; } v; v.f = f;
  unsigned r = v.u + 0x7FFFu + ((v.u >> 16) & 1u);
  return (ushort)(r >> 16);
}
__device__ __forceinline__ float bf2f(ushort h) {
  union { unsigned u; float f; } v; v.u = ((unsigned)h) << 16;
  return v.f;
}

__device__ __forceinline__ int src_of(const int* __restrict__ src, int e) {
  return (e < EE) ? src[e] : (e - EE);
}
__device__ __forceinline__ int dst_of(const int* __restrict__ dst, int e) {
  return (e < EE) ? dst[e] : (e - EE);
}

// ---------------- CSR build ----------------

__global__ void k_zero(int* __restrict__ p, int n) {
  int i = blockIdx.x * blockDim.x + threadIdx.x;
  if (i < n) p[i] = 0;
}

__global__ void k_degree(const int* __restrict__ dst, int* __restrict__ deg) {
  int e = blockIdx.x * blockDim.x + threadIdx.x;
  if (e < EF) atomicAdd(&deg[dst_of(dst, e)], 1);
}

__global__ void k_scan(const int* __restrict__ deg, int* __restrict__ rowstart) {
  __shared__ int wsum[16];
  __shared__ int chunk_total;
  __shared__ int carry_s;
  int tid = threadIdx.x;
  int lane = tid & 63;
  int wid = tid >> 6;
  if (tid == 0) carry_s = 0;
  __syncthreads();
  for (int base = 0; base < NN; base += 1024) {
    int i = base + tid;
    int v = (i < NN) ? deg[i] : 0;
    int s = v;
#pragma unroll
    for (int off = 1; off < 64; off <<= 1) {
      int t = __shfl_up(s, off, 64);
      if (lane >= off) s += t;
    }
    if (lane == 63) wsum[wid] = s;
    __syncthreads();
    if (wid == 0) {
      int wv = (lane < 16) ? wsum[lane] : 0;
      int ws2 = wv;
#pragma unroll
      for (int off = 1; off < 16; off <<= 1) {
        int t = __shfl_up(ws2, off, 64);
        if (lane >= off) ws2 += t;
      }
      if (lane < 16) wsum[lane] = ws2 - wv;
      if (lane == 15) chunk_total = ws2;
    }
    __syncthreads();
    int excl = carry_s + wsum[wid] + (s - v);
    if (i < NN) rowstart[i] = excl;
    __syncthreads();
    if (tid == 0) carry_s += chunk_total;
    __syncthreads();
  }
  if (tid == 0) rowstart[NN] = carry_s;
}

__global__ void k_bucket(const int* __restrict__ src, const int* __restrict__ dst,
                         const int* __restrict__ etypes,
                         const int* __restrict__ rowstart, int* __restrict__ cursor,
                         int* __restrict__ csr_se, int* __restrict__ csr_dst) {
  int e = blockIdx.x * blockDim.x + threadIdx.x;
  if (e < EF) {
    int d = dst_of(dst, e);
    int pos = atomicAdd(&cursor[d], 1);
    int i = rowstart[d] + pos;
    csr_se[i] = src_of(src, e) | (etypes[e] << 16);
    csr_dst[i] = d;
  }
}

// ---------------- splits / weight prep ----------------

__global__ void k_split(const float* __restrict__ x, ushort* __restrict__ hi,
                        ushort* __restrict__ lo, int n) {
  int i = blockIdx.x * blockDim.x + threadIdx.x;
  if (i < n) {
    float v = x[i];
    ushort h = f2bf(v);
    hi[i] = h;
    lo[i] = f2bf(v - bf2f(h));
  }
}

// Wc[t] = Wih @ W[t]  (192x64), bvec[t] = b[t] @ Wih^T (192)
__global__ void k_combine(const float* __restrict__ Wih, const float* __restrict__ gW,
                          const float* __restrict__ gb,
                          float* __restrict__ Wcfp, float* __restrict__ bvec) {
  int idx = blockIdx.x * 256 + threadIdx.x;
  if (idx < 2 * 192 * 64) {
    int t = idx / (192 * 64);
    int rem = idx - t * (192 * 64);
    int c = rem >> 6, k = rem & 63;
    const float* wr = Wih + c * 64;
    const float* wc = gW + t * 64 * 64 + k;
    float s = 0.f;
#pragma unroll 8
    for (int j = 0; j < 64; j++) s += wr[j] * wc[j * 64];
    Wcfp[idx] = s;
  } else if (idx < 2 * 192 * 64 + 384) {
    int f = idx - 2 * 192 * 64;
    int t = f / 192, c = f - t * 192;
    const float* wr = Wih + c * 64;
    const float* bb = gb + t * 64;
    float s = 0.f;
#pragma unroll 8
    for (int j = 0; j < 64; j++) s += bb[j] * wr[j];
    bvec[f] = s;
  }
}

// layer weights -> hi/lo region: wsrc | wdst | WF[c][k] (k: Wc0 | Wc1 | Whh)
__global__ void k_split_w(const float* __restrict__ Wsrc, const float* __restrict__ Wdst,
                          const float* __restrict__ Wcfp, const float* __restrict__ Whh,
                          ushort* __restrict__ whi, ushort* __restrict__ wlo) {
  int i = blockIdx.x * blockDim.x + threadIdx.x;
  if (i >= WL_TOTAL) return;
  float v;
  if (i < WL_WDST) v = Wsrc[i];
  else if (i < WL_WF) v = Wdst[i - WL_WDST];
  else {
    int f = i - WL_WF;
    int c = f / 192, k = f - c * 192;
    if (k < 64) v = Wcfp[c * 64 + k];
    else if (k < 128) v = Wcfp[192 * 64 + c * 64 + (k - 64)];
    else v = Whh[c * 64 + (k - 128)];
  }
  ushort h = f2bf(v);
  whi[i] = h;
  wlo[i] = f2bf(v - bf2f(h));
}

// ---------------- MFMA matmuls ----------------

// el = x@Wsrc^T+bsrc ; er = x@Wdst^T+bdst. Block: 16 rows, 4 waves (mat x nt-half).
__global__ __launch_bounds__(256) void k_linear2_mfma(
    const ushort* __restrict__ xhi, const ushort* __restrict__ xlo,
    const ushort* __restrict__ whi, const ushort* __restrict__ wlo,
    const float* __restrict__ bsrc, const float* __restrict__ bdst,
    float* __restrict__ el, float* __restrict__ er) {
  int tid = threadIdx.x;
  int lane = tid & 63;
  int wid = tid >> 6;
  int mat = wid & 1, nh = wid >> 1;
  int tile = blockIdx.x;
  int nloc = lane & 15, q = lane >> 4;

  floatx4 acc[2];
  acc[0] = (floatx4)0.f; acc[1] = (floatx4)0.f;

#pragma unroll
  for (int ks = 0; ks < 2; ks++) {
    size_t aoff = (size_t)(tile * 16 + nloc) * DD + ks * 32 + q * 8;
    frag_u ah, al;
    ah.u = *(const uintx4*)(xhi + aoff);
    al.u = *(const uintx4*)(xlo + aoff);
#pragma unroll
    for (int j = 0; j < 2; j++) {
      int nt = nh * 2 + j;
      size_t boff = (size_t)(mat ? WL_WDST : 0) + (nt * 16 + nloc) * DD + ks * 32 + q * 8;
      frag_u bh, bl;
      bh.u = *(const uintx4*)(whi + boff);
      bl.u = *(const uintx4*)(wlo + boff);
      acc[j] = __builtin_amdgcn_mfma_f32_16x16x32_bf16(ah.s, bh.s, acc[j], 0, 0, 0);
      acc[j] = __builtin_amdgcn_mfma_f32_16x16x32_bf16(ah.s, bl.s, acc[j], 0, 0, 0);
      acc[j] = __builtin_amdgcn_mfma_f32_16x16x32_bf16(al.s, bh.s, acc[j], 0, 0, 0);
    }
  }

  float* outp = mat ? er : el;
  const float* bb = mat ? bdst : bsrc;
#pragma unroll
  for (int j = 0; j < 2; j++) {
    int col = (nh * 2 + j) * 16 + nloc;
    float b0 = bb[col];
#pragma unroll
    for (int r = 0; r < 4; r++) {
      int row = tile * 16 + q * 4 + r;
      outp[(size_t)row * DD + col] = acc[j][r] + b0;
    }
  }
}

// fused GRU via combined weights: K=192 [Wc0|Wc1|Whh]; A = S0,S1,h.
// Block: 16 rows, 4 waves (nt = wid). cnt-bias epilogue.
__global__ __launch_bounds__(256) void k_gru_mfma(
    const ushort* __restrict__ s0hi, const ushort* __restrict__ s0lo,
    const ushort* __restrict__ s1hi, const ushort* __restrict__ s1lo,
    const ushort* __restrict__ hhi, const ushort* __restrict__ hlo,
    const float* __restrict__ h_in,
    const ushort* __restrict__ wfh, const ushort* __restrict__ wfl,  // WF base
    const float* __restrict__ bih, const float* __restrict__ bhh,
    const float* __restrict__ bvec,  // [2][192]
    const float* __restrict__ cnt0, const float* __restrict__ cnt1,
    float* __restrict__ h_out, ushort* __restrict__ ohi, ushort* __restrict__ olo) {
  int tid = threadIdx.x;
  int lane = tid & 63;
  int nt = tid >> 6;
  int tile = blockIdx.x;
  int nloc = lane & 15, q = lane >> 4;

  floatx4 ar = (floatx4)0.f, az = (floatx4)0.f;
  floatx4 aic = (floatx4)0.f, ahc = (floatx4)0.f;

#pragma unroll
  for (int ks = 0; ks < 6; ks++) {
    const ushort* Ahi = (ks < 2) ? s0hi : (ks < 4) ? s1hi : hhi;
    const ushort* Alo = (ks < 2) ? s0lo : (ks < 4) ? s1lo : hlo;
    size_t aoff = (size_t)(tile * 16 + nloc) * DD + (ks & 1) * 32 + q * 8;
    frag_u fah, fal;
    fah.u = *(const uintx4*)(Ahi + aoff);
    fal.u = *(const uintx4*)(Alo + aoff);
#pragma unroll
    for (int g = 0; g < 3; g++) {
      int c = g * 64 + nt * 16 + nloc;
      size_t boff = (size_t)c * 192 + ks * 32 + q * 8;
      frag_u bh, bl;
      bh.u = *(const uintx4*)(wfh + boff);
      bl.u = *(const uintx4*)(wfl + boff);
      floatx4* acc = (g == 0) ? &ar : (g == 1) ? &az : ((ks < 4) ? &aic : &ahc);
      *acc = __builtin_amdgcn_mfma_f32_16x16x32_bf16(fah.s, bh.s, *acc, 0, 0, 0);
      *acc = __builtin_amdgcn_mfma_f32_16x16x32_bf16(fah.s, bl.s, *acc, 0, 0, 0);
      *acc = __builtin_amdgcn_mfma_f32_16x16x32_bf16(fal.s, bh.s, *acc, 0, 0, 0);
    }
  }

  int col = nt * 16 + nloc;
  float bvr0 = bvec[col], bvz0 = bvec[64 + col], bvc0 = bvec[128 + col];
  float bvr1 = bvec[192 + col], bvz1 = bvec[256 + col], bvc1 = bvec[320 + col];
  float br = bih[col] + bhh[col];
  float bz = bih[64 + col] + bhh[64 + col];
  float bic = bih[128 + col], bhc = bhh[128 + col];
#pragma unroll
  for (int r = 0; r < 4; r++) {
    int row = tile * 16 + q * 4 + r;
    float c0v = cnt0[row], c1v = cnt1[row];
    float rr = 1.f / (1.f + expf(-(ar[r] + br + c0v * bvr0 + c1v * bvr1)));
    float zz = 1.f / (1.f + expf(-(az[r] + bz + c0v * bvz0 + c1v * bvz1)));
    float icv = aic[r] + bic + c0v * bvc0 + c1v * bvc1;
    float hcv = ahc[r] + bhc;
    float cc = tanhf(icv + rr * hcv);
    float hp = h_in[(size_t)row * DD + col];
    float hn = (1.f - zz) * cc + zz * hp;
    size_t o = (size_t)row * DD + col;
    h_out[o] = hn;
    ushort hh = f2bf(hn);
    ohi[o] = hh;
    olo[o] = f2bf(hn - bf2f(hh));
  }
}

// ---------------- edge / gather kernels ----------------

__global__ __launch_bounds__(256) void k_edge_score(
    const float* __restrict__ el, const float* __restrict__ er,
    const float* __restrict__ attn,
    const int* __restrict__ csr_se, const int* __restrict__ csr_dst,
    float* __restrict__ score_csr) {
  __shared__ float sattn[DD];
  int tid = threadIdx.x;
  if (tid < DD) sattn[tid] = attn[tid];
  __syncthreads();
  int i = blockIdx.x * 256 + tid;
  if (i >= EF) return;
  int s = csr_se[i] & 0xFFFF;
  int t = csr_dst[i];
  const float4* a4 = (const float4*)(el + (size_t)s * DD);
  const float4* b4 = (const float4*)(er + (size_t)t * DD);
  float acc = 0.f;
#pragma unroll 4
  for (int qq = 0; qq < 16; qq++) {
    float4 ea = a4[qq];
    float4 eb = b4[qq];
    float v;
    v = ea.x + eb.x; v = (v > 0.f) ? v : NEG_SLOPE * v; acc = fmaf(v, sattn[4 * qq + 0], acc);
    v = ea.y + eb.y; v = (v > 0.f) ? v : NEG_SLOPE * v; acc = fmaf(v, sattn[4 * qq + 1], acc);
    v = ea.z + eb.z; v = (v > 0.f) ? v : NEG_SLOPE * v; acc = fmaf(v, sattn[4 * qq + 2], acc);
    v = ea.w + eb.w; v = (v > 0.f) ? v : NEG_SLOPE * v; acc = fmaf(v, sattn[4 * qq + 3], acc);
  }
  score_csr[i] = acc;
}

__global__ __launch_bounds__(256) void k_gat_agg(
    const float* __restrict__ el, float* __restrict__ score_csr,
    const int* __restrict__ rowstart, const int* __restrict__ csr_se,
    float* __restrict__ out, ushort* __restrict__ ohi, ushort* __restrict__ olo) {
  int lane = threadIdx.x & 63;
  int n = blockIdx.x * 4 + (threadIdx.x >> 6);
  if (n >= NN) return;
  int r0 = rowstart[n], r1 = rowstart[n + 1];
  float m = -INFINITY;
  for (int i = r0 + lane; i < r1; i += 64) m = fmaxf(m, score_csr[i]);
#pragma unroll
  for (int off = 32; off > 0; off >>= 1) m = fmaxf(m, __shfl_xor(m, off, 64));
  float den = 0.f;
  for (int i = r0 + lane; i < r1; i += 64) {
    float ex = __expf(score_csr[i] - m);
    den += ex;
    score_csr[i] = ex;
  }
#pragma unroll
  for (int off = 32; off > 0; off >>= 1) den += __shfl_xor(den, off, 64);
  float a0 = 0.f, a1 = 0.f, a2 = 0.f, a3 = 0.f;
  int i = r0;
  for (; i + 4 <= r1; i += 4) {
    int s0 = csr_se[i + 0] & 0xFFFF, s1 = csr_se[i + 1] & 0xFFFF;
    int s2 = csr_se[i + 2] & 0xFFFF, s3 = csr_se[i + 3] & 0xFFFF;
    float w0 = score_csr[i + 0], w1 = score_csr[i + 1];
    float w2 = score_csr[i + 2], w3 = score_csr[i + 3];
    a0 = fmaf(w0, el[(size_t)s0 * DD + lane], a0);
    a1 = fmaf(w1, el[(size_t)s1 * DD + lane], a1);
    a2 = fmaf(w2, el[(size_t)s2 * DD + lane], a2);
    a3 = fmaf(w3, el[(size_t)s3 * DD + lane], a3);
  }
  for (; i < r1; i++) {
    a0 = fmaf(score_csr[i], el[(size_t)(csr_se[i] & 0xFFFF) * DD + lane], a0);
  }
  float o = ((a0 + a1) + (a2 + a3)) / den;
  o = (o > 0.f) ? o : expm1f(o);
  size_t oo = (size_t)n * DD + lane;
  out[oo] = o;
  ushort h = f2bf(o);
  ohi[oo] = h;
  olo[oo] = f2bf(o - bf2f(h));
}

// per node: S_t[n] = sum of h[src] over in-edges of type t; counts per type.
__global__ __launch_bounds__(256) void k_ggc_gather(
    const float* __restrict__ h,
    const int* __restrict__ rowstart, const int* __restrict__ csr_se,
    ushort* __restrict__ s0hi, ushort* __restrict__ s0lo,
    ushort* __restrict__ s1hi, ushort* __restrict__ s1lo,
    float* __restrict__ cnt0, float* __restrict__ cnt1) {
  int lane = threadIdx.x & 63;
  int n = blockIdx.x * 4 + (threadIdx.x >> 6);
  if (n >= NN) return;
  int r0 = rowstart[n], r1 = rowstart[n + 1];
  float sa0 = 0.f, sa1 = 0.f, sb0 = 0.f, sb1 = 0.f;  // type0 x2, type1 x2
  int c1 = 0;
  int i = r0;
  for (; i + 4 <= r1; i += 4) {
    int se0 = csr_se[i + 0], se1 = csr_se[i + 1];
    int se2 = csr_se[i + 2], se3 = csr_se[i + 3];
    float v0 = h[(size_t)(se0 & 0xFFFF) * DD + lane];
    float v1 = h[(size_t)(se1 & 0xFFFF) * DD + lane];
    float v2 = h[(size_t)(se2 & 0xFFFF) * DD + lane];
    float v3 = h[(size_t)(se3 & 0xFFFF) * DD + lane];
    if (se0 >> 16) { sb0 += v0; c1++; } else sa0 += v0;
    if (se1 >> 16) { sb1 += v1; c1++; } else sa1 += v1;
    if (se2 >> 16) { sb0 += v2; c1++; } else sa0 += v2;
    if (se3 >> 16) { sb1 += v3; c1++; } else sa1 += v3;
  }
  for (; i < r1; i++) {
    int se = csr_se[i];
    float v = h[(size_t)(se & 0xFFFF) * DD + lane];
    if (se >> 16) { sb0 += v; c1++; } else sa0 += v;
  }
  float s0 = sa0 + sa1, s1 = sb0 + sb1;
  size_t oo = (size_t)n * DD + lane;
  ushort h0 = f2bf(s0);
  s0hi[oo] = h0;
  s0lo[oo] = f2bf(s0 - bf2f(h0));
  ushort h1 = f2bf(s1);
  s1hi[oo] = h1;
  s1lo[oo] = f2bf(s1 - bf2f(h1));
  if (lane == 0) {
    cnt1[n] = (float)c1;
    cnt0[n] = (float)((r1 - r0) - c1);
  }
}

// ---------------- launch ----------------

extern "C" void kernel_launch(void* const* d_in, const int* in_sizes, int n_in,
                              void* d_out, int out_size, void* d_ws, size_t ws_size,
                              hipStream_t stream) {
  const float* x = (const float*)d_in[0];
  const int* src = (const int*)d_in[1];
  const int* dst = (const int*)d_in[2];
  const int* etypes = (const int*)d_in[3];

  float* out = (float*)d_out;

  float* el = (float*)d_ws;                       // NN*DD
  float* er = el + (size_t)NN * DD;               // NN*DD
  float* big = er + (size_t)NN * DD;              // 2*NN*DD floats
  float* score = big;                             // GAT alias
  ushort* s0hi = (ushort*)big;                    // GGC alias (4 x NN*DD ushort)
  ushort* s0lo = s0hi + (size_t)NN * DD;
  ushort* s1hi = s0lo + (size_t)NN * DD;
  ushort* s1lo = s1hi + (size_t)NN * DD;
  float* htmp = el;                               // GGC alias
  ushort* pA_hi = (ushort*)(big + (size_t)2 * NN * DD);
  ushort* pA_lo = pA_hi + (size_t)NN * DD;
  ushort* pB_hi = pA_lo + (size_t)NN * DD;
  ushort* pB_lo = pB_hi + (size_t)NN * DD;
  float* cnt0 = (float*)(pB_lo + (size_t)NN * DD);
  float* cnt1 = cnt0 + NN;
  float* Wcfp = cnt1 + NN;                        // 2*192*64 (reused per layer)
  float* bvec = Wcfp + 2 * 192 * 64;              // 2 layers x 384
  ushort* whi = (ushort*)(bvec + 2 * 384);        // 2 x WL_TOTAL
  ushort* wlo = whi + 2 * WL_TOTAL;
  int* deg = (int*)(wlo + 2 * WL_TOTAL);
  int* cursor = deg + NN;
  int* rowstart = cursor + NN;
  int* csr_se = rowstart + (NN + 1);
  int* csr_dst = csr_se + EF;

  k_zero<<<(2 * NN + 255) / 256, 256, 0, stream>>>(deg, 2 * NN);
  k_degree<<<(EF + 255) / 256, 256, 0, stream>>>(dst, deg);
  k_scan<<<1, 1024, 0, stream>>>(deg, rowstart);
  k_bucket<<<(EF + 255) / 256, 256, 0, stream>>>(src, dst, etypes, rowstart, cursor,
                                                 csr_se, csr_dst);
  k_split<<<(NN * DD + 255) / 256, 256, 0, stream>>>(x, pB_hi, pB_lo, NN * DD);

  for (int l = 0; l < 2; l++) {
    int base = 4 + 11 * l;
    k_combine<<<98, 256, 0, stream>>>(
        (const float*)d_in[base + 7], (const float*)d_in[base + 5],
        (const float*)d_in[base + 6], Wcfp, bvec + l * 384);
    k_split_w<<<(WL_TOTAL + 255) / 256, 256, 0, stream>>>(
        (const float*)d_in[base + 0], (const float*)d_in[base + 2],
        Wcfp, (const float*)d_in[base + 9],
        whi + l * WL_TOTAL, wlo + l * WL_TOTAL);
  }

  for (int l = 0; l < 2; l++) {
    int base = 4 + 11 * l;
    const float* bsrc = (const float*)d_in[base + 1];
    const float* bdst = (const float*)d_in[base + 3];
    const float* attn = (const float*)d_in[base + 4];
    const float* bih  = (const float*)d_in[base + 8];
    const float* bhh  = (const float*)d_in[base + 10];
    const ushort* lwhi = whi + l * WL_TOTAL;
    const ushort* lwlo = wlo + l * WL_TOTAL;
    const ushort* wfh = lwhi + WL_WF;
    const ushort* wfl = lwlo + WL_WF;
    const float* lbvec = bvec + l * 384;

    const ushort* in_hi = (l == 0) ? pB_hi : pA_hi;
    const ushort* in_lo = (l == 0) ? pB_lo : pA_lo;
    float* emb_gat = out + (size_t)(2 * l) * NN * DD;
    float* emb_ggc = out + (size_t)(2 * l + 1) * NN * DD;

    // GATv2
    k_linear2_mfma<<<NT16, 256, 0, stream>>>(in_hi, in_lo, lwhi, lwlo, bsrc, bdst, el, er);
    k_edge_score<<<(EF + 255) / 256, 256, 0, stream>>>(el, er, attn, csr_se, csr_dst, score);
    k_gat_agg<<<(NN + 3) / 4, 256, 0, stream>>>(el, score, rowstart, csr_se,
                                                emb_gat, pA_hi, pA_lo);

    // GGC step 1 (h = emb_gat, pair = pA)
    k_ggc_gather<<<(NN + 3) / 4, 256, 0, stream>>>(emb_gat, rowstart, csr_se,
                                                   s0hi, s0lo, s1hi, s1lo, cnt0, cnt1);
    k_gru_mfma<<<NT16, 256, 0, stream>>>(s0hi, s0lo, s1hi, s1lo, pA_hi, pA_lo, emb_gat,
                                         wfh, wfl, bih, bhh, lbvec, cnt0, cnt1,
                                         htmp, pB_hi, pB_lo);

    // GGC step 2 (h = htmp, pair = pB); output pair -> pA
    k_ggc_gather<<<(NN + 3) / 4, 256, 0, stream>>>(htmp, rowstart, csr_se,
                                                   s0hi, s0lo, s1hi, s1lo, cnt0, cnt1);
    k_gru_mfma<<<NT16, 256, 0, stream>>>(s0hi, s0lo, s1hi, s1lo, pB_hi, pB_lo, htmp,
                                         wfh, wfl, bih, bhh, lbvec, cnt0, cnt1,
                                         emb_ggc, pA_hi, pA_lo);
  }
}

// Round 6
// 773.153 us; speedup vs baseline: 2.3174x; 1.2061x over previous
//
#include <hip/hip_runtime.h>
#include <math.h>

#define NN 50000
#define EE 800000
#define EF (EE + NN)
#define DD 64
#define NEG_SLOPE 0.2f
#define NT16 3125   // NN/16 exactly

// packed per-layer weight frags (ushort): 16 linear frags + 72 WF frags,
// each frag = 64 lanes x (8 hi + 8 lo) ushorts = 1024 ushorts
#define WPK_WF    16384
#define WPK_TOTAL (88 * 1024)

typedef unsigned short ushort;
typedef __attribute__((ext_vector_type(8))) short short8;
typedef __attribute__((ext_vector_type(4))) float floatx4;
typedef __attribute__((ext_vector_type(4))) unsigned int uintx4;

union frag_u { uintx4 u; short8 s; };

__device__ __forceinline__ ushort f2bf(float f) {
  union { float f; unsigned u; } v; v.f = f;
  unsigned r = v.u + 0x7FFFu + ((v.u >> 16) & 1u);
  return (ushort)(r >> 16);
}
__device__ __forceinline__ float bf2f(ushort h) {
  union { unsigned u; float f; } v; v.u = ((unsigned)h) << 16;
  return v.f;
}

// load 8 contiguous fp32 and split to bf16 hi/lo fragments in-register
__device__ __forceinline__ void split8(const float* __restrict__ p, short8& hi, short8& lo) {
  float4 f0 = *(const float4*)p;
  float4 f1 = *(const float4*)(p + 4);
  float v[8] = {f0.x, f0.y, f0.z, f0.w, f1.x, f1.y, f1.z, f1.w};
#pragma unroll
  for (int j = 0; j < 8; j++) {
    ushort h = f2bf(v[j]);
    hi[j] = (short)h;
    lo[j] = (short)f2bf(v[j] - bf2f(h));
  }
}

__device__ __forceinline__ int src_of(const int* __restrict__ src, int e) {
  return (e < EE) ? src[e] : (e - EE);
}
__device__ __forceinline__ int dst_of(const int* __restrict__ dst, int e) {
  return (e < EE) ? dst[e] : (e - EE);
}

// ---------------- CSR build ----------------

__global__ void k_zero(int* __restrict__ p, int n) {
  int i = blockIdx.x * blockDim.x + threadIdx.x;
  if (i < n) p[i] = 0;
}

__global__ void k_degree(const int* __restrict__ dst, int* __restrict__ deg) {
  int e = blockIdx.x * blockDim.x + threadIdx.x;
  if (e < EF) atomicAdd(&deg[dst_of(dst, e)], 1);
}

__global__ void k_scan(const int* __restrict__ deg, int* __restrict__ rowstart) {
  __shared__ int wsum[16];
  __shared__ int chunk_total;
  __shared__ int carry_s;
  int tid = threadIdx.x;
  int lane = tid & 63;
  int wid = tid >> 6;
  if (tid == 0) carry_s = 0;
  __syncthreads();
  for (int base = 0; base < NN; base += 1024) {
    int i = base + tid;
    int v = (i < NN) ? deg[i] : 0;
    int s = v;
#pragma unroll
    for (int off = 1; off < 64; off <<= 1) {
      int t = __shfl_up(s, off, 64);
      if (lane >= off) s += t;
    }
    if (lane == 63) wsum[wid] = s;
    __syncthreads();
    if (wid == 0) {
      int wv = (lane < 16) ? wsum[lane] : 0;
      int ws2 = wv;
#pragma unroll
      for (int off = 1; off < 16; off <<= 1) {
        int t = __shfl_up(ws2, off, 64);
        if (lane >= off) ws2 += t;
      }
      if (lane < 16) wsum[lane] = ws2 - wv;
      if (lane == 15) chunk_total = ws2;
    }
    __syncthreads();
    int excl = carry_s + wsum[wid] + (s - v);
    if (i < NN) rowstart[i] = excl;
    __syncthreads();
    if (tid == 0) carry_s += chunk_total;
    __syncthreads();
  }
  if (tid == 0) rowstart[NN] = carry_s;
}

__global__ void k_bucket(const int* __restrict__ src, const int* __restrict__ dst,
                         const int* __restrict__ etypes,
                         const int* __restrict__ rowstart, int* __restrict__ cursor,
                         int* __restrict__ csr_se, int* __restrict__ csr_dst) {
  int e = blockIdx.x * blockDim.x + threadIdx.x;
  if (e < EF) {
    int d = dst_of(dst, e);
    int pos = atomicAdd(&cursor[d], 1);
    int i = rowstart[d] + pos;
    csr_se[i] = src_of(src, e) | (etypes[e] << 16);
    csr_dst[i] = d;
  }
}

// ---------------- weight prep ----------------

// Wc[t] = Wih @ W[t]  (192x64), bvec[t] = b[t] @ Wih^T (192)
__global__ void k_combine(const float* __restrict__ Wih, const float* __restrict__ gW,
                          const float* __restrict__ gb,
                          float* __restrict__ Wcfp, float* __restrict__ bvec) {
  int idx = blockIdx.x * 256 + threadIdx.x;
  if (idx < 2 * 192 * 64) {
    int t = idx / (192 * 64);
    int rem = idx - t * (192 * 64);
    int c = rem >> 6, k = rem & 63;
    const float* wr = Wih + c * 64;
    const float* wc = gW + t * 64 * 64 + k;
    float s = 0.f;
#pragma unroll 8
    for (int j = 0; j < 64; j++) s += wr[j] * wc[j * 64];
    Wcfp[idx] = s;
  } else if (idx < 2 * 192 * 64 + 384) {
    int f = idx - 2 * 192 * 64;
    int t = f / 192, c = f - t * 192;
    const float* wr = Wih + c * 64;
    const float* bb = gb + t * 64;
    float s = 0.f;
#pragma unroll 8
    for (int j = 0; j < 64; j++) s += bb[j] * wr[j];
    bvec[f] = s;
  }
}

// pack one layer's weights into coalesced frag layout.
// lin frag id = (mat*4+nt)*2+ks (16); WF frag id = 16 + (ks*3+g)*4+nt (72).
__global__ void k_split_w(const float* __restrict__ Wsrc, const float* __restrict__ Wdst,
                          const float* __restrict__ Wcfp, const float* __restrict__ Whh,
                          ushort* __restrict__ wpk) {
  int t = blockIdx.x * 256 + threadIdx.x;
  if (t >= 88 * 64) return;
  int frag = t >> 6, lane = t & 63;
  int nloc = lane & 15, q = lane >> 4;
  float v[8];
  if (frag < 16) {
    int mat = frag >> 3;
    int nt = (frag >> 1) & 3;
    int ks = frag & 1;
    const float* W = mat ? Wdst : Wsrc;
    const float* row = W + (nt * 16 + nloc) * 64 + ks * 32 + q * 8;
#pragma unroll
    for (int j = 0; j < 8; j++) v[j] = row[j];
  } else {
    int f = frag - 16;
    int nt = f & 3;
    int gg = (f >> 2) % 3;
    int ks = f / 12;
    int c = gg * 64 + nt * 16 + nloc;
    int k0 = ks * 32 + q * 8;
#pragma unroll
    for (int j = 0; j < 8; j++) {
      int kk = k0 + j;
      v[j] = (kk < 64) ? Wcfp[c * 64 + kk]
           : (kk < 128) ? Wcfp[192 * 64 + c * 64 + (kk - 64)]
                        : Whh[c * 64 + (kk - 128)];
    }
  }
  ushort* d = wpk + (size_t)frag * 1024 + lane * 16;
#pragma unroll
  for (int j = 0; j < 8; j++) {
    ushort h = f2bf(v[j]);
    d[j] = h;
    d[8 + j] = f2bf(v[j] - bf2f(h));
  }
}

// ---------------- MFMA matmuls (fp32 A with in-reg split) ----------------

// el = x@Wsrc^T+bsrc ; er = x@Wdst^T+bdst. Block: 16 rows, 4 waves (mat x nt-half).
__global__ __launch_bounds__(256) void k_linear2_mfma(
    const float* __restrict__ x, const ushort* __restrict__ wpk,
    const float* __restrict__ bsrc, const float* __restrict__ bdst,
    float* __restrict__ el, float* __restrict__ er) {
  int tid = threadIdx.x;
  int lane = tid & 63;
  int wid = tid >> 6;
  int mat = wid & 1, nh = wid >> 1;
  int tile = blockIdx.x;
  int nloc = lane & 15, q = lane >> 4;

  floatx4 acc[2];
  acc[0] = (floatx4)0.f; acc[1] = (floatx4)0.f;

#pragma unroll
  for (int ks = 0; ks < 2; ks++) {
    const float* ap = x + (size_t)(tile * 16 + nloc) * DD + ks * 32 + q * 8;
    short8 ah, al;
    split8(ap, ah, al);
#pragma unroll
    for (int j = 0; j < 2; j++) {
      int nt = nh * 2 + j;
      const ushort* bp = wpk + ((size_t)((mat * 4 + nt) * 2 + ks)) * 1024 + lane * 16;
      frag_u bh, bl;
      bh.u = *(const uintx4*)bp;
      bl.u = *(const uintx4*)(bp + 8);
      acc[j] = __builtin_amdgcn_mfma_f32_16x16x32_bf16(ah, bh.s, acc[j], 0, 0, 0);
      acc[j] = __builtin_amdgcn_mfma_f32_16x16x32_bf16(ah, bl.s, acc[j], 0, 0, 0);
      acc[j] = __builtin_amdgcn_mfma_f32_16x16x32_bf16(al, bh.s, acc[j], 0, 0, 0);
    }
  }

  float* outp = mat ? er : el;
  const float* bb = mat ? bdst : bsrc;
#pragma unroll
  for (int j = 0; j < 2; j++) {
    int col = (nh * 2 + j) * 16 + nloc;
    float b0 = bb[col];
#pragma unroll
    for (int r = 0; r < 4; r++) {
      int row = tile * 16 + q * 4 + r;
      outp[(size_t)row * DD + col] = acc[j][r] + b0;
    }
  }
}

// fused GRU: K=192 [Wc0|Wc1|Whh]; A = S0,S1,h (all fp32, in-reg split).
__global__ __launch_bounds__(256) void k_gru_mfma(
    const float* __restrict__ S0, const float* __restrict__ S1,
    const float* __restrict__ h_in,
    const ushort* __restrict__ wpk,
    const float* __restrict__ bih, const float* __restrict__ bhh,
    const float* __restrict__ bvec,
    const float* __restrict__ cnt0, const float* __restrict__ cnt1,
    float* __restrict__ h_out) {
  int tid = threadIdx.x;
  int lane = tid & 63;
  int nt = tid >> 6;
  int tile = blockIdx.x;
  int nloc = lane & 15, q = lane >> 4;
  const ushort* wf = wpk + WPK_WF;

  floatx4 ar = (floatx4)0.f, az = (floatx4)0.f;
  floatx4 aic = (floatx4)0.f, ahc = (floatx4)0.f;

#pragma unroll
  for (int ks = 0; ks < 6; ks++) {
    const float* A = (ks < 2) ? S0 : (ks < 4) ? S1 : h_in;
    const float* ap = A + (size_t)(tile * 16 + nloc) * DD + (ks & 1) * 32 + q * 8;
    short8 fah, fal;
    split8(ap, fah, fal);
#pragma unroll
    for (int g = 0; g < 3; g++) {
      const ushort* bp = wf + ((size_t)((ks * 3 + g) * 4 + nt)) * 1024 + lane * 16;
      frag_u bh, bl;
      bh.u = *(const uintx4*)bp;
      bl.u = *(const uintx4*)(bp + 8);
      floatx4* acc = (g == 0) ? &ar : (g == 1) ? &az : ((ks < 4) ? &aic : &ahc);
      *acc = __builtin_amdgcn_mfma_f32_16x16x32_bf16(fah, bh.s, *acc, 0, 0, 0);
      *acc = __builtin_amdgcn_mfma_f32_16x16x32_bf16(fah, bl.s, *acc, 0, 0, 0);
      *acc = __builtin_amdgcn_mfma_f32_16x16x32_bf16(fal, bh.s, *acc, 0, 0, 0);
    }
  }

  int col = nt * 16 + nloc;
  float bvr0 = bvec[col], bvz0 = bvec[64 + col], bvc0 = bvec[128 + col];
  float bvr1 = bvec[192 + col], bvz1 = bvec[256 + col], bvc1 = bvec[320 + col];
  float br = bih[col] + bhh[col];
  float bz = bih[64 + col] + bhh[64 + col];
  float bic = bih[128 + col], bhc = bhh[128 + col];
#pragma unroll
  for (int r = 0; r < 4; r++) {
    int row = tile * 16 + q * 4 + r;
    float c0v = cnt0[row], c1v = cnt1[row];
    float rr = 1.f / (1.f + expf(-(ar[r] + br + c0v * bvr0 + c1v * bvr1)));
    float zz = 1.f / (1.f + expf(-(az[r] + bz + c0v * bvz0 + c1v * bvz1)));
    float icv = aic[r] + bic + c0v * bvc0 + c1v * bvc1;
    float hcv = ahc[r] + bhc;
    float cc = tanhf(icv + rr * hcv);
    float hp = h_in[(size_t)row * DD + col];
    h_out[(size_t)row * DD + col] = (1.f - zz) * cc + zz * hp;
  }
}

// ---------------- edge / gather kernels ----------------

__global__ __launch_bounds__(256) void k_edge_score(
    const float* __restrict__ el, const float* __restrict__ er,
    const float* __restrict__ attn,
    const int* __restrict__ csr_se, const int* __restrict__ csr_dst,
    float* __restrict__ score_csr) {
  __shared__ float sattn[DD];
  int tid = threadIdx.x;
  if (tid < DD) sattn[tid] = attn[tid];
  __syncthreads();
  int i = blockIdx.x * 256 + tid;
  if (i >= EF) return;
  int s = csr_se[i] & 0xFFFF;
  int t = csr_dst[i];
  const float4* a4 = (const float4*)(el + (size_t)s * DD);
  const float4* b4 = (const float4*)(er + (size_t)t * DD);
  float acc = 0.f;
#pragma unroll 4
  for (int qq = 0; qq < 16; qq++) {
    float4 ea = a4[qq];
    float4 eb = b4[qq];
    float v;
    v = ea.x + eb.x; v = (v > 0.f) ? v : NEG_SLOPE * v; acc = fmaf(v, sattn[4 * qq + 0], acc);
    v = ea.y + eb.y; v = (v > 0.f) ? v : NEG_SLOPE * v; acc = fmaf(v, sattn[4 * qq + 1], acc);
    v = ea.z + eb.z; v = (v > 0.f) ? v : NEG_SLOPE * v; acc = fmaf(v, sattn[4 * qq + 2], acc);
    v = ea.w + eb.w; v = (v > 0.f) ? v : NEG_SLOPE * v; acc = fmaf(v, sattn[4 * qq + 3], acc);
  }
  score_csr[i] = acc;
}

// wave per node: softmax (lane-strided) then float4 4-edge weighted gather.
__global__ __launch_bounds__(256) void k_gat_agg(
    const float* __restrict__ el, float* __restrict__ score_csr,
    const int* __restrict__ rowstart, const int* __restrict__ csr_se,
    float* __restrict__ out) {
  int lane = threadIdx.x & 63;
  int n = blockIdx.x * 4 + (threadIdx.x >> 6);
  if (n >= NN) return;
  int r0 = rowstart[n], r1 = rowstart[n + 1];
  float m = -INFINITY;
  for (int i = r0 + lane; i < r1; i += 64) m = fmaxf(m, score_csr[i]);
#pragma unroll
  for (int off = 32; off > 0; off >>= 1) m = fmaxf(m, __shfl_xor(m, off, 64));
  float den = 0.f;
  for (int i = r0 + lane; i < r1; i += 64) {
    float ex = __expf(score_csr[i] - m);
    den += ex;
    score_csr[i] = ex;
  }
#pragma unroll
  for (int off = 32; off > 0; off >>= 1) den += __shfl_xor(den, off, 64);

  int eg = lane >> 4, c4 = lane & 15;
  const float4* el4 = (const float4*)el;
  float ax0 = 0.f, ay0 = 0.f, az0 = 0.f, aw0 = 0.f;
  float ax1 = 0.f, ay1 = 0.f, az1 = 0.f, aw1 = 0.f;
  for (int i = r0; i < r1; i += 8) {
    int e0 = i + eg, e1 = i + 4 + eg;
    if (e0 < r1) {
      int s = csr_se[e0] & 0xFFFF;
      float w = score_csr[e0];
      float4 v = el4[(size_t)s * 16 + c4];
      ax0 = fmaf(w, v.x, ax0); ay0 = fmaf(w, v.y, ay0);
      az0 = fmaf(w, v.z, az0); aw0 = fmaf(w, v.w, aw0);
    }
    if (e1 < r1) {
      int s = csr_se[e1] & 0xFFFF;
      float w = score_csr[e1];
      float4 v = el4[(size_t)s * 16 + c4];
      ax1 = fmaf(w, v.x, ax1); ay1 = fmaf(w, v.y, ay1);
      az1 = fmaf(w, v.z, az1); aw1 = fmaf(w, v.w, aw1);
    }
  }
  ax0 += ax1; ay0 += ay1; az0 += az1; aw0 += aw1;
#pragma unroll
  for (int off = 16; off <= 32; off <<= 1) {
    ax0 += __shfl_xor(ax0, off, 64);
    ay0 += __shfl_xor(ay0, off, 64);
    az0 += __shfl_xor(az0, off, 64);
    aw0 += __shfl_xor(aw0, off, 64);
  }
  if (eg == 0) {
    float inv = 1.f / den;
    float4 o;
    o.x = ax0 * inv; o.y = ay0 * inv; o.z = az0 * inv; o.w = aw0 * inv;
    o.x = (o.x > 0.f) ? o.x : expm1f(o.x);
    o.y = (o.y > 0.f) ? o.y : expm1f(o.y);
    o.z = (o.z > 0.f) ? o.z : expm1f(o.z);
    o.w = (o.w > 0.f) ? o.w : expm1f(o.w);
    ((float4*)out)[(size_t)n * 16 + c4] = o;
  }
}

// wave per node: float4 4-edge gather of h[src] by etype; fp32 S0,S1 + counts.
__global__ __launch_bounds__(256) void k_ggc_gather(
    const float* __restrict__ h,
    const int* __restrict__ rowstart, const int* __restrict__ csr_se,
    float* __restrict__ S0, float* __restrict__ S1,
    float* __restrict__ cnt0, float* __restrict__ cnt1) {
  int lane = threadIdx.x & 63;
  int n = blockIdx.x * 4 + (threadIdx.x >> 6);
  if (n >= NN) return;
  int r0 = rowstart[n], r1 = rowstart[n + 1];
  int eg = lane >> 4, c4 = lane & 15;
  const float4* h4 = (const float4*)h;
  float t0x = 0.f, t0y = 0.f, t0z = 0.f, t0w = 0.f;
  float t1x = 0.f, t1y = 0.f, t1z = 0.f, t1w = 0.f;
  float u0x = 0.f, u0y = 0.f, u0z = 0.f, u0w = 0.f;
  float u1x = 0.f, u1y = 0.f, u1z = 0.f, u1w = 0.f;
  int c1 = 0;
  for (int i = r0; i < r1; i += 8) {
    int e0 = i + eg, e1 = i + 4 + eg;
    if (e0 < r1) {
      int se = csr_se[e0];
      float4 v = h4[(size_t)(se & 0xFFFF) * 16 + c4];
      float m1 = (float)(se >> 16), m0 = 1.f - m1;
      t0x = fmaf(m0, v.x, t0x); t0y = fmaf(m0, v.y, t0y);
      t0z = fmaf(m0, v.z, t0z); t0w = fmaf(m0, v.w, t0w);
      t1x = fmaf(m1, v.x, t1x); t1y = fmaf(m1, v.y, t1y);
      t1z = fmaf(m1, v.z, t1z); t1w = fmaf(m1, v.w, t1w);
      if (c4 == 0) c1 += (se >> 16);
    }
    if (e1 < r1) {
      int se = csr_se[e1];
      float4 v = h4[(size_t)(se & 0xFFFF) * 16 + c4];
      float m1 = (float)(se >> 16), m0 = 1.f - m1;
      u0x = fmaf(m0, v.x, u0x); u0y = fmaf(m0, v.y, u0y);
      u0z = fmaf(m0, v.z, u0z); u0w = fmaf(m0, v.w, u0w);
      u1x = fmaf(m1, v.x, u1x); u1y = fmaf(m1, v.y, u1y);
      u1z = fmaf(m1, v.z, u1z); u1w = fmaf(m1, v.w, u1w);
      if (c4 == 0) c1 += (se >> 16);
    }
  }
  t0x += u0x; t0y += u0y; t0z += u0z; t0w += u0w;
  t1x += u1x; t1y += u1y; t1z += u1z; t1w += u1w;
#pragma unroll
  for (int off = 16; off <= 32; off <<= 1) {
    t0x += __shfl_xor(t0x, off, 64); t0y += __shfl_xor(t0y, off, 64);
    t0z += __shfl_xor(t0z, off, 64); t0w += __shfl_xor(t0w, off, 64);
    t1x += __shfl_xor(t1x, off, 64); t1y += __shfl_xor(t1y, off, 64);
    t1z += __shfl_xor(t1z, off, 64); t1w += __shfl_xor(t1w, off, 64);
    c1 += __shfl_xor(c1, off, 64);
  }
  if (eg == 0) {
    float4 a; a.x = t0x; a.y = t0y; a.z = t0z; a.w = t0w;
    float4 b; b.x = t1x; b.y = t1y; b.z = t1z; b.w = t1w;
    ((float4*)S0)[(size_t)n * 16 + c4] = a;
    ((float4*)S1)[(size_t)n * 16 + c4] = b;
  }
  if (lane == 0) {
    cnt1[n] = (float)c1;
    cnt0[n] = (float)((r1 - r0) - c1);
  }
}

// ---------------- launch ----------------

extern "C" void kernel_launch(void* const* d_in, const int* in_sizes, int n_in,
                              void* d_out, int out_size, void* d_ws, size_t ws_size,
                              hipStream_t stream) {
  const float* x = (const float*)d_in[0];
  const int* src = (const int*)d_in[1];
  const int* dst = (const int*)d_in[2];
  const int* etypes = (const int*)d_in[3];

  float* out = (float*)d_out;

  float* el = (float*)d_ws;                       // NN*DD  (alias: htmp in GGC)
  float* er = el + (size_t)NN * DD;               // NN*DD
  float* big = er + (size_t)NN * DD;              // 2*NN*DD: score (GAT) / S0,S1 (GGC)
  float* score = big;
  float* S0 = big;
  float* S1 = big + (size_t)NN * DD;
  float* htmp = el;
  float* cnt0 = big + (size_t)2 * NN * DD;        // NN
  float* cnt1 = cnt0 + NN;                        // NN
  float* Wcfp = cnt1 + NN;                        // 2*192*64
  float* bvec = Wcfp + 2 * 192 * 64;              // 2 x 384
  ushort* wpk = (ushort*)(bvec + 2 * 384);        // 2 x WPK_TOTAL
  int* deg = (int*)(wpk + 2 * WPK_TOTAL);
  int* cursor = deg + NN;
  int* rowstart = cursor + NN;
  int* csr_se = rowstart + (NN + 1);
  int* csr_dst = csr_se + EF;

  k_zero<<<(2 * NN + 255) / 256, 256, 0, stream>>>(deg, 2 * NN);
  k_degree<<<(EF + 255) / 256, 256, 0, stream>>>(dst, deg);
  k_scan<<<1, 1024, 0, stream>>>(deg, rowstart);
  k_bucket<<<(EF + 255) / 256, 256, 0, stream>>>(src, dst, etypes, rowstart, cursor,
                                                 csr_se, csr_dst);

  for (int l = 0; l < 2; l++) {
    int base = 4 + 11 * l;
    k_combine<<<98, 256, 0, stream>>>(
        (const float*)d_in[base + 7], (const float*)d_in[base + 5],
        (const float*)d_in[base + 6], Wcfp, bvec + l * 384);
    k_split_w<<<22, 256, 0, stream>>>(
        (const float*)d_in[base + 0], (const float*)d_in[base + 2],
        Wcfp, (const float*)d_in[base + 9], wpk + (size_t)l * WPK_TOTAL);
  }

  for (int l = 0; l < 2; l++) {
    int base = 4 + 11 * l;
    const float* bsrc = (const float*)d_in[base + 1];
    const float* bdst = (const float*)d_in[base + 3];
    const float* attn = (const float*)d_in[base + 4];
    const float* bih  = (const float*)d_in[base + 8];
    const float* bhh  = (const float*)d_in[base + 10];
    const ushort* lwpk = wpk + (size_t)l * WPK_TOTAL;
    const float* lbvec = bvec + l * 384;

    const float* xin = (l == 0) ? x : (out + 1 * (size_t)NN * DD);
    float* emb_gat = out + (size_t)(2 * l) * NN * DD;
    float* emb_ggc = out + (size_t)(2 * l + 1) * NN * DD;

    // GATv2
    k_linear2_mfma<<<NT16, 256, 0, stream>>>(xin, lwpk, bsrc, bdst, el, er);
    k_edge_score<<<(EF + 255) / 256, 256, 0, stream>>>(el, er, attn, csr_se, csr_dst, score);
    k_gat_agg<<<(NN + 3) / 4, 256, 0, stream>>>(el, score, rowstart, csr_se, emb_gat);

    // GGC step 1 (h = emb_gat)
    k_ggc_gather<<<(NN + 3) / 4, 256, 0, stream>>>(emb_gat, rowstart, csr_se,
                                                   S0, S1, cnt0, cnt1);
    k_gru_mfma<<<NT16, 256, 0, stream>>>(S0, S1, emb_gat, lwpk, bih, bhh, lbvec,
                                         cnt0, cnt1, htmp);

    // GGC step 2 (h = htmp)
    k_ggc_gather<<<(NN + 3) / 4, 256, 0, stream>>>(htmp, rowstart, csr_se,
                                                   S0, S1, cnt0, cnt1);
    k_gru_mfma<<<NT16, 256, 0, stream>>>(S0, S1, htmp, lwpk, bih, bhh, lbvec,
                                         cnt0, cnt1, emb_ggc);
  }
}

// Round 7
// 715.872 us; speedup vs baseline: 2.5028x; 1.0800x over previous
//
#include <hip/hip_runtime.h>
#include <math.h>

#define NN 50000
#define EE 800000
#define EF (EE + NN)
#define DD 64
#define NEG_SLOPE 0.2f
#define NT16 3125   // NN/16 exactly

// packed per-layer weight frags (ushort): 16 linear frags + 72 WF frags,
// each frag = 64 lanes x (8 hi + 8 lo) ushorts = 1024 ushorts
#define WPK_WF    16384
#define WPK_TOTAL (88 * 1024)

typedef unsigned short ushort;
typedef __attribute__((ext_vector_type(8))) short short8;
typedef __attribute__((ext_vector_type(4))) float floatx4;
typedef __attribute__((ext_vector_type(4))) unsigned int uintx4;

union frag_u { uintx4 u; short8 s; };

__device__ __forceinline__ ushort f2bf(float f) {
  union { float f; unsigned u; } v; v.f = f;
  unsigned r = v.u + 0x7FFFu + ((v.u >> 16) & 1u);
  return (ushort)(r >> 16);
}
__device__ __forceinline__ float bf2f(ushort h) {
  union { unsigned u; float f; } v; v.u = ((unsigned)h) << 16;
  return v.f;
}

// load 8 contiguous fp32 and split to bf16 hi/lo fragments in-register
__device__ __forceinline__ void split8(const float* __restrict__ p, short8& hi, short8& lo) {
  float4 f0 = *(const float4*)p;
  float4 f1 = *(const float4*)(p + 4);
  float v[8] = {f0.x, f0.y, f0.z, f0.w, f1.x, f1.y, f1.z, f1.w};
#pragma unroll
  for (int j = 0; j < 8; j++) {
    ushort h = f2bf(v[j]);
    hi[j] = (short)h;
    lo[j] = (short)f2bf(v[j] - bf2f(h));
  }
}

__device__ __forceinline__ int src_of(const int* __restrict__ src, int e) {
  return (e < EE) ? src[e] : (e - EE);
}
__device__ __forceinline__ int dst_of(const int* __restrict__ dst, int e) {
  return (e < EE) ? dst[e] : (e - EE);
}

// ---------------- CSR build ----------------

__global__ void k_zero(int* __restrict__ p, int n) {
  int i = blockIdx.x * blockDim.x + threadIdx.x;
  if (i < n) p[i] = 0;
}

__global__ void k_degree(const int* __restrict__ dst, int* __restrict__ deg) {
  int e = blockIdx.x * blockDim.x + threadIdx.x;
  if (e < EF) atomicAdd(&deg[dst_of(dst, e)], 1);
}

// single block, 1024 threads, 4 elems/thread: exclusive scan of deg -> rowstart
__global__ void k_scan(const int* __restrict__ deg, int* __restrict__ rowstart) {
  __shared__ int wsum[16];
  __shared__ int chunk_total;
  __shared__ int carry_s;
  int tid = threadIdx.x;
  int lane = tid & 63;
  int wid = tid >> 6;
  if (tid == 0) carry_s = 0;
  __syncthreads();
  for (int base = 0; base < NN; base += 4096) {
    int i0 = base + tid * 4;
    int v0 = (i0 + 0 < NN) ? deg[i0 + 0] : 0;
    int v1 = (i0 + 1 < NN) ? deg[i0 + 1] : 0;
    int v2 = (i0 + 2 < NN) ? deg[i0 + 2] : 0;
    int v3 = (i0 + 3 < NN) ? deg[i0 + 3] : 0;
    int t0 = v0, t1 = t0 + v1, t2 = t1 + v2, t3 = t2 + v3;
    int s = t3;
#pragma unroll
    for (int off = 1; off < 64; off <<= 1) {
      int t = __shfl_up(s, off, 64);
      if (lane >= off) s += t;
    }
    if (lane == 63) wsum[wid] = s;
    __syncthreads();
    if (wid == 0) {
      int wv = (lane < 16) ? wsum[lane] : 0;
      int ws2 = wv;
#pragma unroll
      for (int off = 1; off < 16; off <<= 1) {
        int t = __shfl_up(ws2, off, 64);
        if (lane >= off) ws2 += t;
      }
      if (lane < 16) wsum[lane] = ws2 - wv;
      if (lane == 15) chunk_total = ws2;
    }
    __syncthreads();
    int excl = carry_s + wsum[wid] + (s - t3);
    if (i0 + 0 < NN) rowstart[i0 + 0] = excl;
    if (i0 + 1 < NN) rowstart[i0 + 1] = excl + t0;
    if (i0 + 2 < NN) rowstart[i0 + 2] = excl + t1;
    if (i0 + 3 < NN) rowstart[i0 + 3] = excl + t2;
    __syncthreads();
    if (tid == 0) carry_s += chunk_total;
    __syncthreads();
  }
  if (tid == 0) rowstart[NN] = carry_s;
}

// bucket edges by dst; single 4B scatter per edge: src|etype<<16
__global__ void k_bucket(const int* __restrict__ src, const int* __restrict__ dst,
                         const int* __restrict__ etypes,
                         const int* __restrict__ rowstart, int* __restrict__ cursor,
                         int* __restrict__ csr_se) {
  int e = blockIdx.x * blockDim.x + threadIdx.x;
  if (e < EF) {
    int d = dst_of(dst, e);
    int pos = atomicAdd(&cursor[d], 1);
    csr_se[rowstart[d] + pos] = src_of(src, e) | (etypes[e] << 16);
  }
}

// ---------------- weight prep ----------------

// Wc[t] = Wih @ W[t]  (192x64), bvec[t] = b[t] @ Wih^T (192)
__global__ void k_combine(const float* __restrict__ Wih, const float* __restrict__ gW,
                          const float* __restrict__ gb,
                          float* __restrict__ Wcfp, float* __restrict__ bvec) {
  int idx = blockIdx.x * 256 + threadIdx.x;
  if (idx < 2 * 192 * 64) {
    int t = idx / (192 * 64);
    int rem = idx - t * (192 * 64);
    int c = rem >> 6, k = rem & 63;
    const float* wr = Wih + c * 64;
    const float* wc = gW + t * 64 * 64 + k;
    float s = 0.f;
#pragma unroll 8
    for (int j = 0; j < 64; j++) s += wr[j] * wc[j * 64];
    Wcfp[idx] = s;
  } else if (idx < 2 * 192 * 64 + 384) {
    int f = idx - 2 * 192 * 64;
    int t = f / 192, c = f - t * 192;
    const float* wr = Wih + c * 64;
    const float* bb = gb + t * 64;
    float s = 0.f;
#pragma unroll 8
    for (int j = 0; j < 64; j++) s += bb[j] * wr[j];
    bvec[f] = s;
  }
}

// pack one layer's weights into coalesced frag layout.
// lin frag id = (mat*4+nt)*2+ks (16); WF frag id = 16 + (ks*3+g)*4+nt (72).
__global__ void k_split_w(const float* __restrict__ Wsrc, const float* __restrict__ Wdst,
                          const float* __restrict__ Wcfp, const float* __restrict__ Whh,
                          ushort* __restrict__ wpk) {
  int t = blockIdx.x * 256 + threadIdx.x;
  if (t >= 88 * 64) return;
  int frag = t >> 6, lane = t & 63;
  int nloc = lane & 15, q = lane >> 4;
  float v[8];
  if (frag < 16) {
    int mat = frag >> 3;
    int nt = (frag >> 1) & 3;
    int ks = frag & 1;
    const float* W = mat ? Wdst : Wsrc;
    const float* row = W + (nt * 16 + nloc) * 64 + ks * 32 + q * 8;
#pragma unroll
    for (int j = 0; j < 8; j++) v[j] = row[j];
  } else {
    int f = frag - 16;
    int nt = f & 3;
    int gg = (f >> 2) % 3;
    int ks = f / 12;
    int c = gg * 64 + nt * 16 + nloc;
    int k0 = ks * 32 + q * 8;
#pragma unroll
    for (int j = 0; j < 8; j++) {
      int kk = k0 + j;
      v[j] = (kk < 64) ? Wcfp[c * 64 + kk]
           : (kk < 128) ? Wcfp[192 * 64 + c * 64 + (kk - 64)]
                        : Whh[c * 64 + (kk - 128)];
    }
  }
  ushort* d = wpk + (size_t)frag * 1024 + lane * 16;
#pragma unroll
  for (int j = 0; j < 8; j++) {
    ushort h = f2bf(v[j]);
    d[j] = h;
    d[8 + j] = f2bf(v[j] - bf2f(h));
  }
}

// ---------------- MFMA matmuls (fp32 A with in-reg split) ----------------

// el = x@Wsrc^T+bsrc ; er = x@Wdst^T+bdst. Block: 16 rows, 4 waves (mat x nt-half).
__global__ __launch_bounds__(256) void k_linear2_mfma(
    const float* __restrict__ x, const ushort* __restrict__ wpk,
    const float* __restrict__ bsrc, const float* __restrict__ bdst,
    float* __restrict__ el, float* __restrict__ er) {
  int tid = threadIdx.x;
  int lane = tid & 63;
  int wid = tid >> 6;
  int mat = wid & 1, nh = wid >> 1;
  int tile = blockIdx.x;
  int nloc = lane & 15, q = lane >> 4;

  floatx4 acc[2];
  acc[0] = (floatx4)0.f; acc[1] = (floatx4)0.f;

#pragma unroll
  for (int ks = 0; ks < 2; ks++) {
    const float* ap = x + (size_t)(tile * 16 + nloc) * DD + ks * 32 + q * 8;
    short8 ah, al;
    split8(ap, ah, al);
#pragma unroll
    for (int j = 0; j < 2; j++) {
      int nt = nh * 2 + j;
      const ushort* bp = wpk + ((size_t)((mat * 4 + nt) * 2 + ks)) * 1024 + lane * 16;
      frag_u bh, bl;
      bh.u = *(const uintx4*)bp;
      bl.u = *(const uintx4*)(bp + 8);
      acc[j] = __builtin_amdgcn_mfma_f32_16x16x32_bf16(ah, bh.s, acc[j], 0, 0, 0);
      acc[j] = __builtin_amdgcn_mfma_f32_16x16x32_bf16(ah, bl.s, acc[j], 0, 0, 0);
      acc[j] = __builtin_amdgcn_mfma_f32_16x16x32_bf16(al, bh.s, acc[j], 0, 0, 0);
    }
  }

  float* outp = mat ? er : el;
  const float* bb = mat ? bdst : bsrc;
#pragma unroll
  for (int j = 0; j < 2; j++) {
    int col = (nh * 2 + j) * 16 + nloc;
    float b0 = bb[col];
#pragma unroll
    for (int r = 0; r < 4; r++) {
      int row = tile * 16 + q * 4 + r;
      outp[(size_t)row * DD + col] = acc[j][r] + b0;
    }
  }
}

// fused GRU: K=192 [Wc0|Wc1|Whh]; A = S0,S1,h (all fp32, in-reg split).
__global__ __launch_bounds__(256) void k_gru_mfma(
    const float* __restrict__ S0, const float* __restrict__ S1,
    const float* __restrict__ h_in,
    const ushort* __restrict__ wpk,
    const float* __restrict__ bih, const float* __restrict__ bhh,
    const float* __restrict__ bvec,
    const float* __restrict__ cnt0, const float* __restrict__ cnt1,
    float* __restrict__ h_out) {
  int tid = threadIdx.x;
  int lane = tid & 63;
  int nt = tid >> 6;
  int tile = blockIdx.x;
  int nloc = lane & 15, q = lane >> 4;
  const ushort* wf = wpk + WPK_WF;

  floatx4 ar = (floatx4)0.f, az = (floatx4)0.f;
  floatx4 aic = (floatx4)0.f, ahc = (floatx4)0.f;

#pragma unroll
  for (int ks = 0; ks < 6; ks++) {
    const float* A = (ks < 2) ? S0 : (ks < 4) ? S1 : h_in;
    const float* ap = A + (size_t)(tile * 16 + nloc) * DD + (ks & 1) * 32 + q * 8;
    short8 fah, fal;
    split8(ap, fah, fal);
#pragma unroll
    for (int g = 0; g < 3; g++) {
      const ushort* bp = wf + ((size_t)((ks * 3 + g) * 4 + nt)) * 1024 + lane * 16;
      frag_u bh, bl;
      bh.u = *(const uintx4*)bp;
      bl.u = *(const uintx4*)(bp + 8);
      floatx4* acc = (g == 0) ? &ar : (g == 1) ? &az : ((ks < 4) ? &aic : &ahc);
      *acc = __builtin_amdgcn_mfma_f32_16x16x32_bf16(fah, bh.s, *acc, 0, 0, 0);
      *acc = __builtin_amdgcn_mfma_f32_16x16x32_bf16(fah, bl.s, *acc, 0, 0, 0);
      *acc = __builtin_amdgcn_mfma_f32_16x16x32_bf16(fal, bh.s, *acc, 0, 0, 0);
    }
  }

  int col = nt * 16 + nloc;
  float bvr0 = bvec[col], bvz0 = bvec[64 + col], bvc0 = bvec[128 + col];
  float bvr1 = bvec[192 + col], bvz1 = bvec[256 + col], bvc1 = bvec[320 + col];
  float br = bih[col] + bhh[col];
  float bz = bih[64 + col] + bhh[64 + col];
  float bic = bih[128 + col], bhc = bhh[128 + col];
#pragma unroll
  for (int r = 0; r < 4; r++) {
    int row = tile * 16 + q * 4 + r;
    float c0v = cnt0[row], c1v = cnt1[row];
    float rr = 1.f / (1.f + expf(-(ar[r] + br + c0v * bvr0 + c1v * bvr1)));
    float zz = 1.f / (1.f + expf(-(az[r] + bz + c0v * bvz0 + c1v * bvz1)));
    float icv = aic[r] + bic + c0v * bvc0 + c1v * bvc1;
    float hcv = ahc[r] + bhc;
    float cc = tanhf(icv + rr * hcv);
    float hp = h_in[(size_t)row * DD + col];
    h_out[(size_t)row * DD + col] = (1.f - zz) * cc + zz * hp;
  }
}

// ---------------- fused GAT edge-softmax + aggregation ----------------
// wave per node. Lane = edge-slot(4) x dim-quad(16). Online softmax, score
// recomputed in pass 2 (never materialized).
__global__ __launch_bounds__(256) void k_gat_fused(
    const float* __restrict__ el, const float* __restrict__ er,
    const float* __restrict__ attn,
    const int* __restrict__ rowstart, const int* __restrict__ csr_se,
    float* __restrict__ out) {
  int lane = threadIdx.x & 63;
  int n = blockIdx.x * 4 + (threadIdx.x >> 6);
  if (n >= NN) return;
  int r0 = rowstart[n], r1 = rowstart[n + 1];
  int eg = lane >> 4, c4 = lane & 15;
  const float4* el4 = (const float4*)el;
  float4 erv = ((const float4*)er)[(size_t)n * 16 + c4];
  float4 at4 = ((const float4*)attn)[c4];

  // pass 1: online softmax (m, den) per edge-group
  float m = -1e30f, d = 0.f;
  for (int i = r0; i < r1; i += 4) {
    int e = i + eg;
    float sv = -1e30f;
    bool ok = (e < r1);
    if (ok) {
      int s = csr_se[e] & 0xFFFF;
      float4 v = el4[(size_t)s * 16 + c4];
      float p;
      float t;
      t = v.x + erv.x; t = (t > 0.f) ? t : NEG_SLOPE * t; p = t * at4.x;
      t = v.y + erv.y; t = (t > 0.f) ? t : NEG_SLOPE * t; p = fmaf(t, at4.y, p);
      t = v.z + erv.z; t = (t > 0.f) ? t : NEG_SLOPE * t; p = fmaf(t, at4.z, p);
      t = v.w + erv.w; t = (t > 0.f) ? t : NEG_SLOPE * t; p = fmaf(t, at4.w, p);
#pragma unroll
      for (int off = 1; off <= 8; off <<= 1) p += __shfl_xor(p, off, 64);
      sv = p;
    }
    float mn = fmaxf(m, sv);
    d = d * __expf(m - mn) + (ok ? __expf(sv - mn) : 0.f);
    m = mn;
  }
  // combine the 4 groups
#pragma unroll
  for (int off = 16; off <= 32; off <<= 1) {
    float mo = __shfl_xor(m, off, 64);
    float dd = __shfl_xor(d, off, 64);
    float mn = fmaxf(m, mo);
    d = d * __expf(m - mn) + dd * __expf(mo - mn);
    m = mn;
  }

  // pass 2: weighted gather, score recomputed
  float ax0 = 0.f, ay0 = 0.f, az0 = 0.f, aw0 = 0.f;
  float ax1 = 0.f, ay1 = 0.f, az1 = 0.f, aw1 = 0.f;
  for (int i = r0; i < r1; i += 8) {
    int e0 = i + eg, e1 = i + 4 + eg;
    if (e0 < r1) {
      int s = csr_se[e0] & 0xFFFF;
      float4 v = el4[(size_t)s * 16 + c4];
      float p, t;
      t = v.x + erv.x; t = (t > 0.f) ? t : NEG_SLOPE * t; p = t * at4.x;
      t = v.y + erv.y; t = (t > 0.f) ? t : NEG_SLOPE * t; p = fmaf(t, at4.y, p);
      t = v.z + erv.z; t = (t > 0.f) ? t : NEG_SLOPE * t; p = fmaf(t, at4.z, p);
      t = v.w + erv.w; t = (t > 0.f) ? t : NEG_SLOPE * t; p = fmaf(t, at4.w, p);
#pragma unroll
      for (int off = 1; off <= 8; off <<= 1) p += __shfl_xor(p, off, 64);
      float w = __expf(p - m);
      ax0 = fmaf(w, v.x, ax0); ay0 = fmaf(w, v.y, ay0);
      az0 = fmaf(w, v.z, az0); aw0 = fmaf(w, v.w, aw0);
    }
    if (e1 < r1) {
      int s = csr_se[e1] & 0xFFFF;
      float4 v = el4[(size_t)s * 16 + c4];
      float p, t;
      t = v.x + erv.x; t = (t > 0.f) ? t : NEG_SLOPE * t; p = t * at4.x;
      t = v.y + erv.y; t = (t > 0.f) ? t : NEG_SLOPE * t; p = fmaf(t, at4.y, p);
      t = v.z + erv.z; t = (t > 0.f) ? t : NEG_SLOPE * t; p = fmaf(t, at4.z, p);
      t = v.w + erv.w; t = (t > 0.f) ? t : NEG_SLOPE * t; p = fmaf(t, at4.w, p);
#pragma unroll
      for (int off = 1; off <= 8; off <<= 1) p += __shfl_xor(p, off, 64);
      float w = __expf(p - m);
      ax1 = fmaf(w, v.x, ax1); ay1 = fmaf(w, v.y, ay1);
      az1 = fmaf(w, v.z, az1); aw1 = fmaf(w, v.w, aw1);
    }
  }
  ax0 += ax1; ay0 += ay1; az0 += az1; aw0 += aw1;
#pragma unroll
  for (int off = 16; off <= 32; off <<= 1) {
    ax0 += __shfl_xor(ax0, off, 64);
    ay0 += __shfl_xor(ay0, off, 64);
    az0 += __shfl_xor(az0, off, 64);
    aw0 += __shfl_xor(aw0, off, 64);
  }
  if (eg == 0) {
    float inv = 1.f / d;
    float4 o;
    o.x = ax0 * inv; o.y = ay0 * inv; o.z = az0 * inv; o.w = aw0 * inv;
    o.x = (o.x > 0.f) ? o.x : expm1f(o.x);
    o.y = (o.y > 0.f) ? o.y : expm1f(o.y);
    o.z = (o.z > 0.f) ? o.z : expm1f(o.z);
    o.w = (o.w > 0.f) ? o.w : expm1f(o.w);
    ((float4*)out)[(size_t)n * 16 + c4] = o;
  }
}

// wave per node: float4 4-edge gather of h[src] by etype; fp32 S0,S1 + counts.
__global__ __launch_bounds__(256) void k_ggc_gather(
    const float* __restrict__ h,
    const int* __restrict__ rowstart, const int* __restrict__ csr_se,
    float* __restrict__ S0, float* __restrict__ S1,
    float* __restrict__ cnt0, float* __restrict__ cnt1) {
  int lane = threadIdx.x & 63;
  int n = blockIdx.x * 4 + (threadIdx.x >> 6);
  if (n >= NN) return;
  int r0 = rowstart[n], r1 = rowstart[n + 1];
  int eg = lane >> 4, c4 = lane & 15;
  const float4* h4 = (const float4*)h;
  float t0x = 0.f, t0y = 0.f, t0z = 0.f, t0w = 0.f;
  float t1x = 0.f, t1y = 0.f, t1z = 0.f, t1w = 0.f;
  float u0x = 0.f, u0y = 0.f, u0z = 0.f, u0w = 0.f;
  float u1x = 0.f, u1y = 0.f, u1z = 0.f, u1w = 0.f;
  int c1 = 0;
  for (int i = r0; i < r1; i += 8) {
    int e0 = i + eg, e1 = i + 4 + eg;
    if (e0 < r1) {
      int se = csr_se[e0];
      float4 v = h4[(size_t)(se & 0xFFFF) * 16 + c4];
      float m1 = (float)(se >> 16), m0 = 1.f - m1;
      t0x = fmaf(m0, v.x, t0x); t0y = fmaf(m0, v.y, t0y);
      t0z = fmaf(m0, v.z, t0z); t0w = fmaf(m0, v.w, t0w);
      t1x = fmaf(m1, v.x, t1x); t1y = fmaf(m1, v.y, t1y);
      t1z = fmaf(m1, v.z, t1z); t1w = fmaf(m1, v.w, t1w);
      if (c4 == 0) c1 += (se >> 16);
    }
    if (e1 < r1) {
      int se = csr_se[e1];
      float4 v = h4[(size_t)(se & 0xFFFF) * 16 + c4];
      float m1 = (float)(se >> 16), m0 = 1.f - m1;
      u0x = fmaf(m0, v.x, u0x); u0y = fmaf(m0, v.y, u0y);
      u0z = fmaf(m0, v.z, u0z); u0w = fmaf(m0, v.w, u0w);
      u1x = fmaf(m1, v.x, u1x); u1y = fmaf(m1, v.y, u1y);
      u1z = fmaf(m1, v.z, u1z); u1w = fmaf(m1, v.w, u1w);
      if (c4 == 0) c1 += (se >> 16);
    }
  }
  t0x += u0x; t0y += u0y; t0z += u0z; t0w += u0w;
  t1x += u1x; t1y += u1y; t1z += u1z; t1w += u1w;
#pragma unroll
  for (int off = 16; off <= 32; off <<= 1) {
    t0x += __shfl_xor(t0x, off, 64); t0y += __shfl_xor(t0y, off, 64);
    t0z += __shfl_xor(t0z, off, 64); t0w += __shfl_xor(t0w, off, 64);
    t1x += __shfl_xor(t1x, off, 64); t1y += __shfl_xor(t1y, off, 64);
    t1z += __shfl_xor(t1z, off, 64); t1w += __shfl_xor(t1w, off, 64);
    c1 += __shfl_xor(c1, off, 64);
  }
  if (eg == 0) {
    float4 a; a.x = t0x; a.y = t0y; a.z = t0z; a.w = t0w;
    float4 b; b.x = t1x; b.y = t1y; b.z = t1z; b.w = t1w;
    ((float4*)S0)[(size_t)n * 16 + c4] = a;
    ((float4*)S1)[(size_t)n * 16 + c4] = b;
  }
  if (lane == 0) {
    cnt1[n] = (float)c1;
    cnt0[n] = (float)((r1 - r0) - c1);
  }
}

// ---------------- launch ----------------

extern "C" void kernel_launch(void* const* d_in, const int* in_sizes, int n_in,
                              void* d_out, int out_size, void* d_ws, size_t ws_size,
                              hipStream_t stream) {
  const float* x = (const float*)d_in[0];
  const int* src = (const int*)d_in[1];
  const int* dst = (const int*)d_in[2];
  const int* etypes = (const int*)d_in[3];

  float* out = (float*)d_out;

  float* el = (float*)d_ws;                       // NN*DD  (alias: htmp in GGC)
  float* er = el + (size_t)NN * DD;               // NN*DD
  float* big = er + (size_t)NN * DD;              // 2*NN*DD: S0,S1 (GGC)
  float* S0 = big;
  float* S1 = big + (size_t)NN * DD;
  float* htmp = el;
  float* cnt0 = big + (size_t)2 * NN * DD;        // NN
  float* cnt1 = cnt0 + NN;                        // NN
  float* Wcfp = cnt1 + NN;                        // 2*192*64
  float* bvec = Wcfp + 2 * 192 * 64;              // 2 x 384
  ushort* wpk = (ushort*)(bvec + 2 * 384);        // 2 x WPK_TOTAL
  int* deg = (int*)(wpk + 2 * WPK_TOTAL);
  int* cursor = deg + NN;
  int* rowstart = cursor + NN;
  int* csr_se = rowstart + (NN + 1);

  k_zero<<<(2 * NN + 255) / 256, 256, 0, stream>>>(deg, 2 * NN);
  k_degree<<<(EF + 255) / 256, 256, 0, stream>>>(dst, deg);
  k_scan<<<1, 1024, 0, stream>>>(deg, rowstart);
  k_bucket<<<(EF + 255) / 256, 256, 0, stream>>>(src, dst, etypes, rowstart, cursor,
                                                 csr_se);

  for (int l = 0; l < 2; l++) {
    int base = 4 + 11 * l;
    k_combine<<<98, 256, 0, stream>>>(
        (const float*)d_in[base + 7], (const float*)d_in[base + 5],
        (const float*)d_in[base + 6], Wcfp, bvec + l * 384);
    k_split_w<<<22, 256, 0, stream>>>(
        (const float*)d_in[base + 0], (const float*)d_in[base + 2],
        Wcfp, (const float*)d_in[base + 9], wpk + (size_t)l * WPK_TOTAL);
  }

  for (int l = 0; l < 2; l++) {
    int base = 4 + 11 * l;
    const float* bsrc = (const float*)d_in[base + 1];
    const float* bdst = (const float*)d_in[base + 3];
    const float* attn = (const float*)d_in[base + 4];
    const float* bih  = (const float*)d_in[base + 8];
    const float* bhh  = (const float*)d_in[base + 10];
    const ushort* lwpk = wpk + (size_t)l * WPK_TOTAL;
    const float* lbvec = bvec + l * 384;

    const float* xin = (l == 0) ? x : (out + 1 * (size_t)NN * DD);
    float* emb_gat = out + (size_t)(2 * l) * NN * DD;
    float* emb_ggc = out + (size_t)(2 * l + 1) * NN * DD;

    // GATv2 (projection + fused edge-softmax/aggregation)
    k_linear2_mfma<<<NT16, 256, 0, stream>>>(xin, lwpk, bsrc, bdst, el, er);
    k_gat_fused<<<(NN + 3) / 4, 256, 0, stream>>>(el, er, attn, rowstart, csr_se, emb_gat);

    // GGC step 1 (h = emb_gat)
    k_ggc_gather<<<(NN + 3) / 4, 256, 0, stream>>>(emb_gat, rowstart, csr_se,
                                                   S0, S1, cnt0, cnt1);
    k_gru_mfma<<<NT16, 256, 0, stream>>>(S0, S1, emb_gat, lwpk, bih, bhh, lbvec,
                                         cnt0, cnt1, htmp);

    // GGC step 2 (h = htmp)
    k_ggc_gather<<<(NN + 3) / 4, 256, 0, stream>>>(htmp, rowstart, csr_se,
                                                   S0, S1, cnt0, cnt1);
    k_gru_mfma<<<NT16, 256, 0, stream>>>(S0, S1, htmp, lwpk, bih, bhh, lbvec,
                                         cnt0, cnt1, emb_ggc);
  }
}

// Round 8
// 694.653 us; speedup vs baseline: 2.5792x; 1.0305x over previous
//
#include <hip/hip_runtime.h>
#include <math.h>

#define NN 50000
#define EE 800000
#define EF (EE + NN)
#define DD 64
#define NEG_SLOPE 0.2f
#define NT16 3125   // NN/16 exactly
#define NN2 (2 * NN)

// packed per-layer weight frags (ushort): 16 linear frags + 72 WF frags,
// each frag = 64 lanes x (8 hi + 8 lo) ushorts = 1024 ushorts
#define WPK_WF    16384
#define WPK_TOTAL (88 * 1024)

typedef unsigned short ushort;
typedef __attribute__((ext_vector_type(8))) short short8;
typedef __attribute__((ext_vector_type(4))) float floatx4;
typedef __attribute__((ext_vector_type(4))) unsigned int uintx4;

union frag_u { uintx4 u; short8 s; };

__device__ __forceinline__ ushort f2bf(float f) {
  union { float f; unsigned u; } v; v.f = f;
  unsigned r = v.u + 0x7FFFu + ((v.u >> 16) & 1u);
  return (ushort)(r >> 16);
}
__device__ __forceinline__ float bf2f(ushort h) {
  union { unsigned u; float f; } v; v.u = ((unsigned)h) << 16;
  return v.f;
}

// load 8 contiguous fp32 and split to bf16 hi/lo fragments in-register
__device__ __forceinline__ void split8(const float* __restrict__ p, short8& hi, short8& lo) {
  float4 f0 = *(const float4*)p;
  float4 f1 = *(const float4*)(p + 4);
  float v[8] = {f0.x, f0.y, f0.z, f0.w, f1.x, f1.y, f1.z, f1.w};
#pragma unroll
  for (int j = 0; j < 8; j++) {
    ushort h = f2bf(v[j]);
    hi[j] = (short)h;
    lo[j] = (short)f2bf(v[j] - bf2f(h));
  }
}

__device__ __forceinline__ int src_of(const int* __restrict__ src, int e) {
  return (e < EE) ? src[e] : (e - EE);
}
__device__ __forceinline__ int dst_of(const int* __restrict__ dst, int e) {
  return (e < EE) ? dst[e] : (e - EE);
}

// ---------------- CSR build (type-sorted) ----------------

__global__ void k_zero(int* __restrict__ p, int n) {
  int i = blockIdx.x * blockDim.x + threadIdx.x;
  if (i < n) p[i] = 0;
}

// per-(node,type) degree histogram
__global__ void k_degree(const int* __restrict__ dst, const int* __restrict__ etypes,
                         int* __restrict__ deg2) {
  int e = blockIdx.x * blockDim.x + threadIdx.x;
  if (e < EF) atomicAdd(&deg2[2 * dst_of(dst, e) + etypes[e]], 1);
}

// single block, 1024 threads, 4 elems/thread: exclusive scan of deg2[0..NN2) -> rs2
__global__ void k_scan(const int* __restrict__ deg2, int* __restrict__ rs2) {
  __shared__ int wsum[16];
  __shared__ int chunk_total;
  __shared__ int carry_s;
  int tid = threadIdx.x;
  int lane = tid & 63;
  int wid = tid >> 6;
  if (tid == 0) carry_s = 0;
  __syncthreads();
  for (int base = 0; base < NN2; base += 4096) {
    int i0 = base + tid * 4;
    int v0 = (i0 + 0 < NN2) ? deg2[i0 + 0] : 0;
    int v1 = (i0 + 1 < NN2) ? deg2[i0 + 1] : 0;
    int v2 = (i0 + 2 < NN2) ? deg2[i0 + 2] : 0;
    int v3 = (i0 + 3 < NN2) ? deg2[i0 + 3] : 0;
    int t0 = v0, t1 = t0 + v1, t2 = t1 + v2, t3 = t2 + v3;
    int s = t3;
#pragma unroll
    for (int off = 1; off < 64; off <<= 1) {
      int t = __shfl_up(s, off, 64);
      if (lane >= off) s += t;
    }
    if (lane == 63) wsum[wid] = s;
    __syncthreads();
    if (wid == 0) {
      int wv = (lane < 16) ? wsum[lane] : 0;
      int ws2 = wv;
#pragma unroll
      for (int off = 1; off < 16; off <<= 1) {
        int t = __shfl_up(ws2, off, 64);
        if (lane >= off) ws2 += t;
      }
      if (lane < 16) wsum[lane] = ws2 - wv;
      if (lane == 15) chunk_total = ws2;
    }
    __syncthreads();
    int excl = carry_s + wsum[wid] + (s - t3);
    if (i0 + 0 < NN2) rs2[i0 + 0] = excl;
    if (i0 + 1 < NN2) rs2[i0 + 1] = excl + t0;
    if (i0 + 2 < NN2) rs2[i0 + 2] = excl + t1;
    if (i0 + 3 < NN2) rs2[i0 + 3] = excl + t2;
    __syncthreads();
    if (tid == 0) carry_s += chunk_total;
    __syncthreads();
  }
  if (tid == 0) rs2[NN2] = carry_s;
}

// bucket edges by (dst,type); single 4B scatter per edge: src index
__global__ void k_bucket(const int* __restrict__ src, const int* __restrict__ dst,
                         const int* __restrict__ etypes,
                         const int* __restrict__ rs2, int* __restrict__ cursor2,
                         int* __restrict__ csr_s) {
  int e = blockIdx.x * blockDim.x + threadIdx.x;
  if (e < EF) {
    int slot = 2 * dst_of(dst, e) + etypes[e];
    int pos = atomicAdd(&cursor2[slot], 1);
    csr_s[rs2[slot] + pos] = src_of(src, e);
  }
}

// ---------------- weight prep ----------------

// Wc[t] = Wih @ W[t]  (192x64), bvec[t] = b[t] @ Wih^T (192)
__global__ void k_combine(const float* __restrict__ Wih, const float* __restrict__ gW,
                          const float* __restrict__ gb,
                          float* __restrict__ Wcfp, float* __restrict__ bvec) {
  int idx = blockIdx.x * 256 + threadIdx.x;
  if (idx < 2 * 192 * 64) {
    int t = idx / (192 * 64);
    int rem = idx - t * (192 * 64);
    int c = rem >> 6, k = rem & 63;
    const float* wr = Wih + c * 64;
    const float* wc = gW + t * 64 * 64 + k;
    float s = 0.f;
#pragma unroll 8
    for (int j = 0; j < 64; j++) s += wr[j] * wc[j * 64];
    Wcfp[idx] = s;
  } else if (idx < 2 * 192 * 64 + 384) {
    int f = idx - 2 * 192 * 64;
    int t = f / 192, c = f - t * 192;
    const float* wr = Wih + c * 64;
    const float* bb = gb + t * 64;
    float s = 0.f;
#pragma unroll 8
    for (int j = 0; j < 64; j++) s += bb[j] * wr[j];
    bvec[f] = s;
  }
}

// pack one layer's weights into coalesced frag layout.
// lin frag id = (mat*4+nt)*2+ks (16); WF frag id = 16 + (ks*3+g)*4+nt (72).
__global__ void k_split_w(const float* __restrict__ Wsrc, const float* __restrict__ Wdst,
                          const float* __restrict__ Wcfp, const float* __restrict__ Whh,
                          ushort* __restrict__ wpk) {
  int t = blockIdx.x * 256 + threadIdx.x;
  if (t >= 88 * 64) return;
  int frag = t >> 6, lane = t & 63;
  int nloc = lane & 15, q = lane >> 4;
  float v[8];
  if (frag < 16) {
    int mat = frag >> 3;
    int nt = (frag >> 1) & 3;
    int ks = frag & 1;
    const float* W = mat ? Wdst : Wsrc;
    const float* row = W + (nt * 16 + nloc) * 64 + ks * 32 + q * 8;
#pragma unroll
    for (int j = 0; j < 8; j++) v[j] = row[j];
  } else {
    int f = frag - 16;
    int nt = f & 3;
    int gg = (f >> 2) % 3;
    int ks = f / 12;
    int c = gg * 64 + nt * 16 + nloc;
    int k0 = ks * 32 + q * 8;
#pragma unroll
    for (int j = 0; j < 8; j++) {
      int kk = k0 + j;
      v[j] = (kk < 64) ? Wcfp[c * 64 + kk]
           : (kk < 128) ? Wcfp[192 * 64 + c * 64 + (kk - 64)]
                        : Whh[c * 64 + (kk - 128)];
    }
  }
  ushort* d = wpk + (size_t)frag * 1024 + lane * 16;
#pragma unroll
  for (int j = 0; j < 8; j++) {
    ushort h = f2bf(v[j]);
    d[j] = h;
    d[8 + j] = f2bf(v[j] - bf2f(h));
  }
}

// ---------------- MFMA matmuls (fp32 A with in-reg split) ----------------

__global__ __launch_bounds__(256) void k_linear2_mfma(
    const float* __restrict__ x, const ushort* __restrict__ wpk,
    const float* __restrict__ bsrc, const float* __restrict__ bdst,
    float* __restrict__ el, float* __restrict__ er) {
  int tid = threadIdx.x;
  int lane = tid & 63;
  int wid = tid >> 6;
  int mat = wid & 1, nh = wid >> 1;
  int tile = blockIdx.x;
  int nloc = lane & 15, q = lane >> 4;

  floatx4 acc[2];
  acc[0] = (floatx4)0.f; acc[1] = (floatx4)0.f;

#pragma unroll
  for (int ks = 0; ks < 2; ks++) {
    const float* ap = x + (size_t)(tile * 16 + nloc) * DD + ks * 32 + q * 8;
    short8 ah, al;
    split8(ap, ah, al);
#pragma unroll
    for (int j = 0; j < 2; j++) {
      int nt = nh * 2 + j;
      const ushort* bp = wpk + ((size_t)((mat * 4 + nt) * 2 + ks)) * 1024 + lane * 16;
      frag_u bh, bl;
      bh.u = *(const uintx4*)bp;
      bl.u = *(const uintx4*)(bp + 8);
      acc[j] = __builtin_amdgcn_mfma_f32_16x16x32_bf16(ah, bh.s, acc[j], 0, 0, 0);
      acc[j] = __builtin_amdgcn_mfma_f32_16x16x32_bf16(ah, bl.s, acc[j], 0, 0, 0);
      acc[j] = __builtin_amdgcn_mfma_f32_16x16x32_bf16(al, bh.s, acc[j], 0, 0, 0);
    }
  }

  float* outp = mat ? er : el;
  const float* bb = mat ? bdst : bsrc;
#pragma unroll
  for (int j = 0; j < 2; j++) {
    int col = (nh * 2 + j) * 16 + nloc;
    float b0 = bb[col];
#pragma unroll
    for (int r = 0; r < 4; r++) {
      int row = tile * 16 + q * 4 + r;
      outp[(size_t)row * DD + col] = acc[j][r] + b0;
    }
  }
}

// fused GRU: K=192 [Wc0|Wc1|Whh]; A = S0,S1,h (fp32, in-reg split).
// counts come from rs2 range lengths.
__global__ __launch_bounds__(256) void k_gru_mfma(
    const float* __restrict__ S0, const float* __restrict__ S1,
    const float* __restrict__ h_in,
    const ushort* __restrict__ wpk,
    const float* __restrict__ bih, const float* __restrict__ bhh,
    const float* __restrict__ bvec,
    const int* __restrict__ rs2,
    float* __restrict__ h_out) {
  int tid = threadIdx.x;
  int lane = tid & 63;
  int nt = tid >> 6;
  int tile = blockIdx.x;
  int nloc = lane & 15, q = lane >> 4;
  const ushort* wf = wpk + WPK_WF;

  floatx4 ar = (floatx4)0.f, az = (floatx4)0.f;
  floatx4 aic = (floatx4)0.f, ahc = (floatx4)0.f;

#pragma unroll
  for (int ks = 0; ks < 6; ks++) {
    const float* A = (ks < 2) ? S0 : (ks < 4) ? S1 : h_in;
    const float* ap = A + (size_t)(tile * 16 + nloc) * DD + (ks & 1) * 32 + q * 8;
    short8 fah, fal;
    split8(ap, fah, fal);
#pragma unroll
    for (int g = 0; g < 3; g++) {
      const ushort* bp = wf + ((size_t)((ks * 3 + g) * 4 + nt)) * 1024 + lane * 16;
      frag_u bh, bl;
      bh.u = *(const uintx4*)bp;
      bl.u = *(const uintx4*)(bp + 8);
      floatx4* acc = (g == 0) ? &ar : (g == 1) ? &az : ((ks < 4) ? &aic : &ahc);
      *acc = __builtin_amdgcn_mfma_f32_16x16x32_bf16(fah, bh.s, *acc, 0, 0, 0);
      *acc = __builtin_amdgcn_mfma_f32_16x16x32_bf16(fah, bl.s, *acc, 0, 0, 0);
      *acc = __builtin_amdgcn_mfma_f32_16x16x32_bf16(fal, bh.s, *acc, 0, 0, 0);
    }
  }

  int col = nt * 16 + nloc;
  float bvr0 = bvec[col], bvz0 = bvec[64 + col], bvc0 = bvec[128 + col];
  float bvr1 = bvec[192 + col], bvz1 = bvec[256 + col], bvc1 = bvec[320 + col];
  float br = bih[col] + bhh[col];
  float bz = bih[64 + col] + bhh[64 + col];
  float bic = bih[128 + col], bhc = bhh[128 + col];
#pragma unroll
  for (int r = 0; r < 4; r++) {
    int row = tile * 16 + q * 4 + r;
    int ra = rs2[2 * row], rb = rs2[2 * row + 1], rc = rs2[2 * row + 2];
    float c0v = (float)(rb - ra), c1v = (float)(rc - rb);
    float rr = 1.f / (1.f + expf(-(ar[r] + br + c0v * bvr0 + c1v * bvr1)));
    float zz = 1.f / (1.f + expf(-(az[r] + bz + c0v * bvz0 + c1v * bvz1)));
    float icv = aic[r] + bic + c0v * bvc0 + c1v * bvc1;
    float hcv = ahc[r] + bhc;
    float cc = tanhf(icv + rr * hcv);
    float hp = h_in[(size_t)row * DD + col];
    h_out[(size_t)row * DD + col] = (1.f - zz) * cc + zz * hp;
  }
}

// ---------------- single-pass flash-style GAT ----------------
// wave per node. Lane = edge-slot(4) x dim-quad(16). Online softmax with
// accumulator rescaling; el[src] gathered exactly once.
__global__ __launch_bounds__(256) void k_gat_fused(
    const float* __restrict__ el, const float* __restrict__ er,
    const float* __restrict__ attn,
    const int* __restrict__ rs2, const int* __restrict__ csr_s,
    float* __restrict__ out) {
  int lane = threadIdx.x & 63;
  int n = blockIdx.x * 4 + (threadIdx.x >> 6);
  if (n >= NN) return;
  int r0 = rs2[2 * n], r1 = rs2[2 * n + 2];
  int eg = lane >> 4, c4 = lane & 15;
  const float4* el4 = (const float4*)el;
  float4 erv = ((const float4*)er)[(size_t)n * 16 + c4];
  float4 at4 = ((const float4*)attn)[c4];

  float m = -1e30f, d = 0.f;
  float ax = 0.f, ay = 0.f, az = 0.f, aw = 0.f;
  for (int i = r0; i < r1; i += 4) {
    int e = i + eg;
    if (e < r1) {
      int s = csr_s[e];
      float4 v = el4[(size_t)s * 16 + c4];
      float p, t;
      t = v.x + erv.x; t = (t > 0.f) ? t : NEG_SLOPE * t; p = t * at4.x;
      t = v.y + erv.y; t = (t > 0.f) ? t : NEG_SLOPE * t; p = fmaf(t, at4.y, p);
      t = v.z + erv.z; t = (t > 0.f) ? t : NEG_SLOPE * t; p = fmaf(t, at4.z, p);
      t = v.w + erv.w; t = (t > 0.f) ? t : NEG_SLOPE * t; p = fmaf(t, at4.w, p);
#pragma unroll
      for (int off = 1; off <= 8; off <<= 1) p += __shfl_xor(p, off, 64);
      float mn = fmaxf(m, p);
      float sc = __expf(m - mn);
      float w = __expf(p - mn);
      d = fmaf(d, sc, w);
      ax = fmaf(ax, sc, w * v.x);
      ay = fmaf(ay, sc, w * v.y);
      az = fmaf(az, sc, w * v.z);
      aw = fmaf(aw, sc, w * v.w);
      m = mn;
    }
  }
  // merge the 4 edge-groups
#pragma unroll
  for (int off = 16; off <= 32; off <<= 1) {
    float mo = __shfl_xor(m, off, 64);
    float d2 = __shfl_xor(d, off, 64);
    float bx = __shfl_xor(ax, off, 64);
    float by = __shfl_xor(ay, off, 64);
    float bz = __shfl_xor(az, off, 64);
    float bw = __shfl_xor(aw, off, 64);
    float mn = fmaxf(m, mo);
    float s1 = __expf(m - mn), s2 = __expf(mo - mn);
    d = d * s1 + d2 * s2;
    ax = ax * s1 + bx * s2;
    ay = ay * s1 + by * s2;
    az = az * s1 + bz * s2;
    aw = aw * s1 + bw * s2;
    m = mn;
  }
  if (eg == 0) {
    float inv = 1.f / d;
    float4 o;
    o.x = ax * inv; o.y = ay * inv; o.z = az * inv; o.w = aw * inv;
    o.x = (o.x > 0.f) ? o.x : expm1f(o.x);
    o.y = (o.y > 0.f) ? o.y : expm1f(o.y);
    o.z = (o.z > 0.f) ? o.z : expm1f(o.z);
    o.w = (o.w > 0.f) ? o.w : expm1f(o.w);
    ((float4*)out)[(size_t)n * 16 + c4] = o;
  }
}

// ---------------- GGC gather (type-sorted subranges, maskless) ----------------

__device__ __forceinline__ void gsum(const float4* __restrict__ h4,
                                     const int* __restrict__ csr_s,
                                     int lo, int hi, int eg, int c4,
                                     float& rx, float& ry, float& rz, float& rw) {
  float x0 = 0.f, y0 = 0.f, z0 = 0.f, w0 = 0.f;
  float x1 = 0.f, y1 = 0.f, z1 = 0.f, w1 = 0.f;
  for (int i = lo; i < hi; i += 8) {
    int e0 = i + eg, e1 = i + 4 + eg;
    if (e0 < hi) {
      float4 v = h4[(size_t)csr_s[e0] * 16 + c4];
      x0 += v.x; y0 += v.y; z0 += v.z; w0 += v.w;
    }
    if (e1 < hi) {
      float4 v = h4[(size_t)csr_s[e1] * 16 + c4];
      x1 += v.x; y1 += v.y; z1 += v.z; w1 += v.w;
    }
  }
  rx = x0 + x1; ry = y0 + y1; rz = z0 + z1; rw = w0 + w1;
}

__global__ __launch_bounds__(256) void k_ggc_gather(
    const float* __restrict__ h,
    const int* __restrict__ rs2, const int* __restrict__ csr_s,
    float* __restrict__ S0, float* __restrict__ S1) {
  int lane = threadIdx.x & 63;
  int n = blockIdx.x * 4 + (threadIdx.x >> 6);
  if (n >= NN) return;
  int r0 = rs2[2 * n], rsp = rs2[2 * n + 1], r1 = rs2[2 * n + 2];
  int eg = lane >> 4, c4 = lane & 15;
  const float4* h4 = (const float4*)h;
  float t0x, t0y, t0z, t0w, t1x, t1y, t1z, t1w;
  gsum(h4, csr_s, r0, rsp, eg, c4, t0x, t0y, t0z, t0w);
  gsum(h4, csr_s, rsp, r1, eg, c4, t1x, t1y, t1z, t1w);
#pragma unroll
  for (int off = 16; off <= 32; off <<= 1) {
    t0x += __shfl_xor(t0x, off, 64); t0y += __shfl_xor(t0y, off, 64);
    t0z += __shfl_xor(t0z, off, 64); t0w += __shfl_xor(t0w, off, 64);
    t1x += __shfl_xor(t1x, off, 64); t1y += __shfl_xor(t1y, off, 64);
    t1z += __shfl_xor(t1z, off, 64); t1w += __shfl_xor(t1w, off, 64);
  }
  if (eg == 0) {
    float4 a; a.x = t0x; a.y = t0y; a.z = t0z; a.w = t0w;
    float4 b; b.x = t1x; b.y = t1y; b.z = t1z; b.w = t1w;
    ((float4*)S0)[(size_t)n * 16 + c4] = a;
    ((float4*)S1)[(size_t)n * 16 + c4] = b;
  }
}

// ---------------- launch ----------------

extern "C" void kernel_launch(void* const* d_in, const int* in_sizes, int n_in,
                              void* d_out, int out_size, void* d_ws, size_t ws_size,
                              hipStream_t stream) {
  const float* x = (const float*)d_in[0];
  const int* src = (const int*)d_in[1];
  const int* dst = (const int*)d_in[2];
  const int* etypes = (const int*)d_in[3];

  float* out = (float*)d_out;

  float* el = (float*)d_ws;                       // NN*DD  (alias: htmp in GGC)
  float* er = el + (size_t)NN * DD;               // NN*DD
  float* big = er + (size_t)NN * DD;              // 2*NN*DD: S0,S1 (GGC)
  float* S0 = big;
  float* S1 = big + (size_t)NN * DD;
  float* htmp = el;
  float* Wcfp = big + (size_t)2 * NN * DD;        // 2*192*64
  float* bvec = Wcfp + 2 * 192 * 64;              // 2 x 384
  ushort* wpk = (ushort*)(bvec + 2 * 384);        // 2 x WPK_TOTAL
  int* deg2 = (int*)(wpk + 2 * WPK_TOTAL);        // NN2
  int* cursor2 = deg2 + NN2;                      // NN2
  int* rs2 = cursor2 + NN2;                       // NN2+1
  int* csr_s = rs2 + (NN2 + 1);                   // EF

  k_zero<<<(2 * NN2 + 255) / 256, 256, 0, stream>>>(deg2, 2 * NN2);
  k_degree<<<(EF + 255) / 256, 256, 0, stream>>>(dst, etypes, deg2);
  k_scan<<<1, 1024, 0, stream>>>(deg2, rs2);
  k_bucket<<<(EF + 255) / 256, 256, 0, stream>>>(src, dst, etypes, rs2, cursor2, csr_s);

  for (int l = 0; l < 2; l++) {
    int base = 4 + 11 * l;
    k_combine<<<98, 256, 0, stream>>>(
        (const float*)d_in[base + 7], (const float*)d_in[base + 5],
        (const float*)d_in[base + 6], Wcfp, bvec + l * 384);
    k_split_w<<<22, 256, 0, stream>>>(
        (const float*)d_in[base + 0], (const float*)d_in[base + 2],
        Wcfp, (const float*)d_in[base + 9], wpk + (size_t)l * WPK_TOTAL);
  }

  for (int l = 0; l < 2; l++) {
    int base = 4 + 11 * l;
    const float* bsrc = (const float*)d_in[base + 1];
    const float* bdst = (const float*)d_in[base + 3];
    const float* attn = (const float*)d_in[base + 4];
    const float* bih  = (const float*)d_in[base + 8];
    const float* bhh  = (const float*)d_in[base + 10];
    const ushort* lwpk = wpk + (size_t)l * WPK_TOTAL;
    const float* lbvec = bvec + l * 384;

    const float* xin = (l == 0) ? x : (out + 1 * (size_t)NN * DD);
    float* emb_gat = out + (size_t)(2 * l) * NN * DD;
    float* emb_ggc = out + (size_t)(2 * l + 1) * NN * DD;

    // GATv2 (projection + single-pass flash softmax/aggregation)
    k_linear2_mfma<<<NT16, 256, 0, stream>>>(xin, lwpk, bsrc, bdst, el, er);
    k_gat_fused<<<(NN + 3) / 4, 256, 0, stream>>>(el, er, attn, rs2, csr_s, emb_gat);

    // GGC step 1 (h = emb_gat)
    k_ggc_gather<<<(NN + 3) / 4, 256, 0, stream>>>(emb_gat, rs2, csr_s, S0, S1);
    k_gru_mfma<<<NT16, 256, 0, stream>>>(S0, S1, emb_gat, lwpk, bih, bhh, lbvec,
                                         rs2, htmp);

    // GGC step 2 (h = htmp)
    k_ggc_gather<<<(NN + 3) / 4, 256, 0, stream>>>(htmp, rs2, csr_s, S0, S1);
    k_gru_mfma<<<NT16, 256, 0, stream>>>(S0, S1, htmp, lwpk, bih, bhh, lbvec,
                                         rs2, emb_ggc);
  }
}